// Round 17
// baseline (106.940 us; speedup 1.0000x reference)
//
#include <hip/hip_runtime.h>
#include <hip/hip_bf16.h>

// Problem constants
constexpr int BATCH = 4;
constexpr int NSEQ  = 1024;
constexpr int CDIM  = 768;
constexpr int NHEAD = 12;
constexpr int HDIM  = 64;
constexpr int MTOT  = BATCH * NSEQ;   // 4096
constexpr int QKVN  = 3 * CDIM;       // 2304

typedef __bf16 bf16x8 __attribute__((ext_vector_type(8)));
typedef float  f32x4  __attribute__((ext_vector_type(4)));

__device__ __forceinline__ unsigned short f2bf(float f) {
    unsigned u = __builtin_bit_cast(unsigned, f);
    unsigned r = u + 0x7FFFu + ((u >> 16) & 1u);   // RNE
    return (unsigned short)(r >> 16);
}

#define GLOAD_LDS16(gp, lp)                                                    \
    __builtin_amdgcn_global_load_lds(                                          \
        (const __attribute__((address_space(1))) void*)(gp),                   \
        (__attribute__((address_space(3))) void*)(lp), 16, 0, 0)

// ---------------------------------------------------------------------------
// Prologue converts
// ---------------------------------------------------------------------------
__global__ __launch_bounds__(256) void cvt_f32_bf16(
    const float* __restrict__ in, unsigned short* __restrict__ out, int n4)
{
    int i = blockIdx.x * 256 + threadIdx.x;
    if (i < n4) {
        float4 a = reinterpret_cast<const float4*>(in)[i];
        ushort4 h;
        h.x = f2bf(a.x); h.y = f2bf(a.y); h.z = f2bf(a.z); h.w = f2bf(a.w);
        reinterpret_cast<ushort4*>(out)[i] = h;
    }
}

// in [R][C] f32  ->  out [C][R] bf16  (32x32 tiles)
__global__ __launch_bounds__(256) void tcvt_f32_bf16(
    const float* __restrict__ in, unsigned short* __restrict__ out, int R, int C)
{
    __shared__ unsigned short t[32][33];
    const int c0 = blockIdx.x * 32, r0 = blockIdx.y * 32;
    const int tc = threadIdx.x & 31, tr = threadIdx.x >> 5;  // tr 0..7
    #pragma unroll
    for (int i = 0; i < 4; i++)
        t[tc][tr + 8 * i] = f2bf(in[(size_t)(r0 + tr + 8 * i) * C + c0 + tc]);
    __syncthreads();
    #pragma unroll
    for (int i = 0; i < 4; i++)
        out[(size_t)(c0 + tr + 8 * i) * R + r0 + tc] = t[tr + 8 * i][tc];
}

// ---------------------------------------------------------------------------
// QKV GEMM: xb [4096,768] bf16 @ wt [2304,768] bf16 (pre-transposed) + bias
// -> scatter bf16 into Q*0.125 [B,H,N,64], K [B,H,N,64], Vt [B,H,64,N]
// 128x128 tile (16 MFMA/phase — m97's proven density), BK=32, async
// double-buffer (r10 attn template): K-step t+1 staged via global_load_lds
// BEFORE computing step t. 64B-row LDS swizzle: slot s of row r stored at
// s^((r>>1)&3) (8-way -> 2-way = free); stage source scs=(lane&3)^((lane>>3)&3),
// read slot g^((li>>1)&3). LDS 32KB -> capacity 5/CU >= grid 2.25.
// ---------------------------------------------------------------------------
__global__ __launch_bounds__(256) void qkv_gemm(
    const unsigned short* __restrict__ xb,   // [4096][768]
    const unsigned short* __restrict__ wt,   // [2304][768]
    const float* __restrict__ bias,
    unsigned short* __restrict__ qbuf, unsigned short* __restrict__ kbuf,
    unsigned short* __restrict__ vtbuf)
{
    __shared__ unsigned short A0[128 * 32], A1[128 * 32];
    __shared__ unsigned short B0[128 * 32], B1[128 * 32];
    const int tid  = threadIdx.x;
    const int lane = tid & 63;
    const int wid  = tid >> 6;
    const int wm = (wid >> 1) * 64, wn = (wid & 1) * 64;
    const int g = lane >> 4, li = lane & 15;
    const int m0 = blockIdx.y * 128;
    const int n0 = blockIdx.x * 128;
    const int srow = lane >> 2;                               // 0..15
    const int scs  = ((lane & 3) ^ ((lane >> 3) & 3)) * 8;    // swizzled src col
    const int rsl  = (g ^ ((li >> 1) & 3)) * 8;               // swizzled read col

#define QSTAGE(K0, AD, BD)                                                     \
    {                                                                          \
        _Pragma("unroll") for (int c = 0; c < 2; c++) {                        \
            int row = wid * 32 + c * 16 + srow;                                \
            GLOAD_LDS16(&xb[(size_t)(m0 + row) * CDIM + (K0) + scs],           \
                        (AD) + (wid * 32 + c * 16) * 32);                      \
            GLOAD_LDS16(&wt[(size_t)(n0 + row) * CDIM + (K0) + scs],           \
                        (BD) + (wid * 32 + c * 16) * 32);                      \
        }                                                                      \
    }

#define QCOMPUTE(AS, BS)                                                       \
    {                                                                          \
        bf16x8 a[4], b[4];                                                     \
        _Pragma("unroll") for (int mt = 0; mt < 4; mt++)                       \
            a[mt] = *reinterpret_cast<const bf16x8*>(                          \
                (AS) + (wm + 16 * mt + li) * 32 + rsl);                        \
        _Pragma("unroll") for (int nt = 0; nt < 4; nt++)                       \
            b[nt] = *reinterpret_cast<const bf16x8*>(                          \
                (BS) + (wn + 16 * nt + li) * 32 + rsl);                        \
        _Pragma("unroll") for (int mt = 0; mt < 4; mt++)                       \
            _Pragma("unroll") for (int nt = 0; nt < 4; nt++)                   \
                acc[mt][nt] = __builtin_amdgcn_mfma_f32_16x16x32_bf16(         \
                    a[mt], b[nt], acc[mt][nt], 0, 0, 0);                       \
    }

    f32x4 acc[4][4];
    #pragma unroll
    for (int i = 0; i < 4; i++)
        #pragma unroll
        for (int j = 0; j < 4; j++) acc[i][j] = f32x4{0.f, 0.f, 0.f, 0.f};

    QSTAGE(0, A0, B0);
    __syncthreads();

    for (int j = 0; j < 12; ++j) {
        const int k0 = j * 64;
        QSTAGE(k0 + 32, A1, B1);
        QCOMPUTE(A0, B0);
        __syncthreads();
        if (j < 11) QSTAGE(k0 + 64, A0, B0);
        QCOMPUTE(A1, B1);
        __syncthreads();
    }

    #pragma unroll
    for (int mt = 0; mt < 4; mt++) {
        #pragma unroll
        for (int nt = 0; nt < 4; nt++) {
            int col  = n0 + wn + 16 * nt + li;
            int tsel = col / CDIM;
            int rem  = col - tsel * CDIM;
            int h_ = rem >> 6, d = rem & 63;
            float bv = bias[col];
            float sc = (tsel == 0) ? 0.125f : 1.0f;
            #pragma unroll
            for (int r = 0; r < 4; r++) {
                int m  = m0 + wm + 16 * mt + 4 * g + r;
                int b_ = m >> 10, s = m & 1023;
                unsigned short hv = f2bf((acc[mt][nt][r] + bv) * sc);
                if (tsel == 0)
                    qbuf[(((size_t)b_ * NHEAD + h_) * NSEQ + s) * HDIM + d] = hv;
                else if (tsel == 1)
                    kbuf[(((size_t)b_ * NHEAD + h_) * NSEQ + s) * HDIM + d] = hv;
                else
                    vtbuf[(((size_t)b_ * NHEAD + h_) * HDIM + d) * NSEQ + s] = hv;
            }
        }
    }
#undef QSTAGE
#undef QCOMPUTE
}

// ---------------------------------------------------------------------------
// Flash-style attention — EXACT round-10 structure (best measured: 46.4 us).
// ---------------------------------------------------------------------------
__global__ __launch_bounds__(256, 3) void attn_kernel(
    const unsigned short* __restrict__ qbuf,
    const unsigned short* __restrict__ kbuf,
    const unsigned short* __restrict__ vtbuf,
    const float* __restrict__ bias,     // [H,N,N]
    unsigned short* __restrict__ ybuf)  // [B,N,C] bf16
{
    __shared__ unsigned short Kl[2][64 * 64];  // [k][d] linear, source-swizzled
    __shared__ unsigned short Vl[2][64 * 64];  // V^T [d][k] linear, swizzled
    __shared__ unsigned short Ps[4][16][72];   // per-wave P: [q][k]

    const int tid  = threadIdx.x;
    const int lane = tid & 63;
    const int wid  = tid >> 6;
    const int g = lane >> 4, li = lane & 15;
    const int srow8 = lane >> 3;               // 0..7
    const int scs   = (lane & 7) ^ srow8;      // swizzled source slot (16B units)
    const int bh = blockIdx.y;
    const int b_ = bh / NHEAD, h_ = bh % NHEAD;
    const int qw = blockIdx.x * 64 + wid * 16;

    const unsigned short* qb = qbuf + (size_t)bh * NSEQ * HDIM;
    const unsigned short* kb = kbuf + (size_t)bh * NSEQ * HDIM;
    const unsigned short* vb = vtbuf + (size_t)bh * HDIM * NSEQ;
    const float* bb = bias + (size_t)h_ * NSEQ * NSEQ;

#define STAGE_KV(T, KL, VL)                                                    \
    {                                                                          \
        _Pragma("unroll") for (int i = 0; i < 2; i++) {                        \
            GLOAD_LDS16(kb + (size_t)((T) * 64 + wid * 16 + i * 8 + srow8) * HDIM + scs * 8, \
                        (KL) + (wid * 16 + i * 8) * 64);                       \
            GLOAD_LDS16(vb + (size_t)(wid * 16 + i * 8 + srow8) * NSEQ + (T) * 64 + scs * 8, \
                        (VL) + (wid * 16 + i * 8) * 64);                       \
        }                                                                      \
    }

#define COMPUTE_TILE(KS, VS, T)                                                \
    {                                                                          \
        float bv[4][4];                                                        \
        _Pragma("unroll") for (int kt = 0; kt < 4; kt++)                       \
            _Pragma("unroll") for (int r = 0; r < 4; r++)                      \
                bv[kt][r] = bb[(size_t)(qw + 4 * g + r) * NSEQ + (T) * 64 + 16 * kt + li]; \
        f32x4 sacc[4];                                                         \
        _Pragma("unroll") for (int kt = 0; kt < 4; kt++)                       \
            sacc[kt] = f32x4{0.f, 0.f, 0.f, 0.f};                              \
        _Pragma("unroll") for (int kt = 0; kt < 4; kt++)                       \
            _Pragma("unroll") for (int dd = 0; dd < 2; dd++) {                 \
                bf16x8 kf = *reinterpret_cast<const bf16x8*>(                  \
                    (KS) + (16 * kt + li) * 64 + (((4 * dd + g) ^ (li & 7)) * 8)); \
                sacc[kt] = __builtin_amdgcn_mfma_f32_16x16x32_bf16(qf[dd], kf, sacc[kt], 0, 0, 0); \
            }                                                                  \
        _Pragma("unroll") for (int kt = 0; kt < 4; kt++)                       \
            _Pragma("unroll") for (int r = 0; r < 4; r++) {                    \
                float pv = __expf(sacc[kt][r] + bv[kt][r]);                    \
                lpart[r] += pv;                                                \
                Ps[wid][4 * g + r][16 * kt + li] = f2bf(pv);                   \
            }                                                                  \
        _Pragma("unroll") for (int kk = 0; kk < 2; kk++) {                     \
            bf16x8 pf = *reinterpret_cast<const bf16x8*>(&Ps[wid][li][32 * kk + 8 * g]); \
            _Pragma("unroll") for (int dt = 0; dt < 4; dt++) {                 \
                bf16x8 vf = *reinterpret_cast<const bf16x8*>(                  \
                    (VS) + (16 * dt + li) * 64 + (((4 * kk + g) ^ (li & 7)) * 8)); \
                oacc[dt] = __builtin_amdgcn_mfma_f32_16x16x32_bf16(pf, vf, oacc[dt], 0, 0, 0); \
            }                                                                  \
        }                                                                      \
    }

    bf16x8 qf[2];
    #pragma unroll
    for (int dd = 0; dd < 2; dd++)
        qf[dd] = *reinterpret_cast<const bf16x8*>(&qb[(size_t)(qw + li) * HDIM + 32 * dd + 8 * g]);

    f32x4 oacc[4];
    #pragma unroll
    for (int dt = 0; dt < 4; dt++) oacc[dt] = f32x4{0.f, 0.f, 0.f, 0.f};
    float lpart[4] = {0.f, 0.f, 0.f, 0.f};

    STAGE_KV(0, Kl[0], Vl[0]);
    __syncthreads();

    for (int j = 0; j < 8; ++j) {
        const int tA = 2 * j;
        STAGE_KV(tA + 1, Kl[1], Vl[1]);
        COMPUTE_TILE(Kl[0], Vl[0], tA);
        __syncthreads();

        if (j < 7) STAGE_KV(tA + 2, Kl[0], Vl[0]);
        COMPUTE_TILE(Kl[1], Vl[1], tA + 1);
        __syncthreads();
    }

    float linv[4];
    #pragma unroll
    for (int r = 0; r < 4; r++) {
        float s = lpart[r];
        s += __shfl_xor(s, 1);
        s += __shfl_xor(s, 2);
        s += __shfl_xor(s, 4);
        s += __shfl_xor(s, 8);
        linv[r] = 1.f / s;
    }
    #pragma unroll
    for (int dt = 0; dt < 4; dt++)
        #pragma unroll
        for (int r = 0; r < 4; r++) {
            float o = oacc[dt][r] * linv[r];
            int sq = qw + 4 * g + r;
            ybuf[((size_t)b_ * NSEQ + sq) * CDIM + h_ * HDIM + 16 * dt + li] = f2bf(o);
        }
#undef STAGE_KV
#undef COMPUTE_TILE
}

// ---------------------------------------------------------------------------
// Proj GEMM: ybuf [4096,768] bf16 @ pwt [768,768] bf16 (pre-transposed)
// + proj_b -> fp32 out.  64x128 tile + BK=32 + async dbuf (r16 version).
// ---------------------------------------------------------------------------
__global__ __launch_bounds__(256) void proj_gemm(
    const unsigned short* __restrict__ yb,   // [4096][768]
    const unsigned short* __restrict__ pwt,  // [768][768] (n,k)
    const float* __restrict__ bias, float* __restrict__ out)
{
    __shared__ unsigned short A0[64 * 32], A1[64 * 32];
    __shared__ unsigned short B0[128 * 32], B1[128 * 32];
    const int tid  = threadIdx.x;
    const int lane = tid & 63;
    const int wid  = tid >> 6;
    const int wr = (wid >> 1) * 32, wc = (wid & 1) * 64;
    const int g = lane >> 4, li = lane & 15;
    const int m0 = blockIdx.y * 64;
    const int n0 = blockIdx.x * 128;
    const int srow = lane >> 2;
    const int scol = (lane & 3) * 8;

#define PSTAGE(K0, AD, BD)                                                     \
    {                                                                          \
        GLOAD_LDS16(&yb[(size_t)(m0 + wid * 16 + srow) * CDIM + (K0) + scol],  \
                    (AD) + wid * 16 * 32);                                     \
        _Pragma("unroll") for (int c = 0; c < 2; c++)                          \
            GLOAD_LDS16(&pwt[(size_t)(n0 + wid * 32 + c * 16 + srow) * CDIM + (K0) + scol], \
                        (BD) + (wid * 32 + c * 16) * 32);                      \
    }

#define PCOMPUTE(AS, BS)                                                       \
    {                                                                          \
        bf16x8 a[2], b[4];                                                     \
        _Pragma("unroll") for (int mt = 0; mt < 2; mt++)                       \
            a[mt] = *reinterpret_cast<const bf16x8*>(                          \
                (AS) + (wr + 16 * mt + li) * 32 + 8 * g);                      \
        _Pragma("unroll") for (int nt = 0; nt < 4; nt++)                       \
            b[nt] = *reinterpret_cast<const bf16x8*>(                          \
                (BS) + (wc + 16 * nt + li) * 32 + 8 * g);                      \
        _Pragma("unroll") for (int mt = 0; mt < 2; mt++)                       \
            _Pragma("unroll") for (int nt = 0; nt < 4; nt++)                   \
                acc[mt][nt] = __builtin_amdgcn_mfma_f32_16x16x32_bf16(         \
                    a[mt], b[nt], acc[mt][nt], 0, 0, 0);                       \
    }

    f32x4 acc[2][4];
    #pragma unroll
    for (int i = 0; i < 2; i++)
        #pragma unroll
        for (int j = 0; j < 4; j++) acc[i][j] = f32x4{0.f, 0.f, 0.f, 0.f};

    PSTAGE(0, A0, B0);
    __syncthreads();

    for (int j = 0; j < 12; ++j) {
        const int k0 = j * 64;
        PSTAGE(k0 + 32, A1, B1);
        PCOMPUTE(A0, B0);
        __syncthreads();
        if (j < 11) PSTAGE(k0 + 64, A0, B0);
        PCOMPUTE(A1, B1);
        __syncthreads();
    }

    #pragma unroll
    for (int mt = 0; mt < 2; mt++)
        #pragma unroll
        for (int nt = 0; nt < 4; nt++) {
            int col = n0 + wc + 16 * nt + li;
            float bv = bias[col];
            #pragma unroll
            for (int r = 0; r < 4; r++) {
                int m = m0 + wr + 16 * mt + 4 * g + r;
                out[(size_t)m * CDIM + col] = acc[mt][nt][r] + bv;
            }
        }
#undef PSTAGE
#undef PCOMPUTE
}

extern "C" void kernel_launch(void* const* d_in, const int* in_sizes, int n_in,
                              void* d_out, int out_size, void* d_ws, size_t ws_size,
                              hipStream_t stream) {
    const float* x         = (const float*)d_in[0];
    const float* attn_bias = (const float*)d_in[1];
    const float* qkv_w     = (const float*)d_in[2];
    const float* qkv_b     = (const float*)d_in[3];
    const float* proj_w    = (const float*)d_in[4];
    const float* proj_b    = (const float*)d_in[5];
    float* out = (float*)d_out;

    const size_t per = (size_t)BATCH * NHEAD * NSEQ * HDIM;  // 3,145,728
    unsigned short* qbuf  = (unsigned short*)d_ws;
    unsigned short* kbuf  = qbuf + per;
    unsigned short* vtbuf = kbuf + per;
    unsigned short* xb    = vtbuf + per;
    unsigned short* qwt   = xb + per;                    // [2304][768]
    unsigned short* pwt   = qwt + (size_t)QKVN * CDIM;   // [768][768]
    unsigned short* ybuf  = xb;  // x dead after qkv_gemm

    cvt_f32_bf16<<<(MTOT * CDIM / 4 + 255) / 256, 256, 0, stream>>>(
        x, xb, MTOT * CDIM / 4);
    tcvt_f32_bf16<<<dim3(QKVN / 32, CDIM / 32), 256, 0, stream>>>(
        qkv_w, qwt, CDIM, QKVN);
    tcvt_f32_bf16<<<dim3(CDIM / 32, CDIM / 32), 256, 0, stream>>>(
        proj_w, pwt, CDIM, CDIM);

    qkv_gemm<<<dim3(QKVN / 128, MTOT / 128), 256, 0, stream>>>(
        xb, qwt, qkv_b, qbuf, kbuf, vtbuf);
    attn_kernel<<<dim3(NSEQ / 64, BATCH * NHEAD), 256, 0, stream>>>(
        qbuf, kbuf, vtbuf, attn_bias, ybuf);
    proj_gemm<<<dim3(CDIM / 128, MTOT / 64), 256, 0, stream>>>(
        ybuf, pwt, proj_b, out);
}

// Round 18
// 102.484 us; speedup vs baseline: 1.0435x; 1.0435x over previous
//
#include <hip/hip_runtime.h>
#include <hip/hip_bf16.h>

// Problem constants
constexpr int BATCH = 4;
constexpr int NSEQ  = 1024;
constexpr int CDIM  = 768;
constexpr int NHEAD = 12;
constexpr int HDIM  = 64;
constexpr int MTOT  = BATCH * NSEQ;   // 4096
constexpr int QKVN  = 3 * CDIM;       // 2304

typedef __bf16 bf16x8 __attribute__((ext_vector_type(8)));
typedef float  f32x4  __attribute__((ext_vector_type(4)));

__device__ __forceinline__ unsigned short f2bf(float f) {
    unsigned u = __builtin_bit_cast(unsigned, f);
    unsigned r = u + 0x7FFFu + ((u >> 16) & 1u);   // RNE
    return (unsigned short)(r >> 16);
}

#define GLOAD_LDS16(gp, lp)                                                    \
    __builtin_amdgcn_global_load_lds(                                          \
        (const __attribute__((address_space(1))) void*)(gp),                   \
        (__attribute__((address_space(3))) void*)(lp), 16, 0, 0)

// ---------------------------------------------------------------------------
// Fused prologue: ONE kernel does all three conversions.
//   blocks [0, NB_X)                     : x f32 -> bf16 linear (float4x per thread)
//   blocks [NB_X, NB_X+NB_QW)            : qkv_w [768][2304] -> qwt [2304][768]
//   blocks [NB_X+NB_QW, +NB_PW)          : proj_w [768][768] -> pwt [768][768]^T
// ---------------------------------------------------------------------------
constexpr int NB_X  = MTOT * CDIM / 4 / 256;       // 3072
constexpr int NB_QW = (QKVN / 32) * (CDIM / 32);   // 72*24 = 1728
constexpr int NB_PW = (CDIM / 32) * (CDIM / 32);   // 24*24 = 576

__device__ __forceinline__ void tcvt_tile(
    const float* __restrict__ in, unsigned short* __restrict__ out,
    int R, int C, int c0, int r0, int tid)
{
    __shared__ unsigned short t[32][33];
    const int tc = tid & 31, tr = tid >> 5;  // tr 0..7
    #pragma unroll
    for (int i = 0; i < 4; i++)
        t[tc][tr + 8 * i] = f2bf(in[(size_t)(r0 + tr + 8 * i) * C + c0 + tc]);
    __syncthreads();
    #pragma unroll
    for (int i = 0; i < 4; i++)
        out[(size_t)(c0 + tr + 8 * i) * R + r0 + tc] = t[tr + 8 * i][tc];
}

__global__ __launch_bounds__(256) void prep_kernel(
    const float* __restrict__ x,      unsigned short* __restrict__ xb,
    const float* __restrict__ qkv_w,  unsigned short* __restrict__ qwt,
    const float* __restrict__ proj_w, unsigned short* __restrict__ pwt)
{
    const int bid = blockIdx.x;
    const int tid = threadIdx.x;
    if (bid < NB_X) {
        int i = bid * 256 + tid;
        float4 a = reinterpret_cast<const float4*>(x)[i];
        ushort4 h;
        h.x = f2bf(a.x); h.y = f2bf(a.y); h.z = f2bf(a.z); h.w = f2bf(a.w);
        reinterpret_cast<ushort4*>(xb)[i] = h;
    } else if (bid < NB_X + NB_QW) {
        int t = bid - NB_X;
        tcvt_tile(qkv_w, qwt, CDIM, QKVN, (t % (QKVN / 32)) * 32,
                  (t / (QKVN / 32)) * 32, tid);
    } else {
        int t = bid - NB_X - NB_QW;
        tcvt_tile(proj_w, pwt, CDIM, CDIM, (t % (CDIM / 32)) * 32,
                  (t / (CDIM / 32)) * 32, tid);
    }
}

// ---------------------------------------------------------------------------
// QKV GEMM (r16 variant — lowest timed total): tile 64x128, BK=32, 2-phase
// async double-buffer via global_load_lds. Grid 1152 = 4.5 blocks/CU.
// -> scatter bf16 into Q*0.125 [B,H,N,64], K [B,H,N,64], Vt [B,H,64,N]
// ---------------------------------------------------------------------------
__global__ __launch_bounds__(256) void qkv_gemm(
    const unsigned short* __restrict__ xb,   // [4096][768]
    const unsigned short* __restrict__ wt,   // [2304][768]
    const float* __restrict__ bias,
    unsigned short* __restrict__ qbuf, unsigned short* __restrict__ kbuf,
    unsigned short* __restrict__ vtbuf)
{
    __shared__ unsigned short A0[64 * 32], A1[64 * 32];
    __shared__ unsigned short B0[128 * 32], B1[128 * 32];
    const int tid  = threadIdx.x;
    const int lane = tid & 63;
    const int wid  = tid >> 6;
    const int wr = (wid >> 1) * 32, wc = (wid & 1) * 64;
    const int g = lane >> 4, li = lane & 15;
    const int m0 = blockIdx.y * 64;
    const int n0 = blockIdx.x * 128;
    const int srow = lane >> 2;          // 0..15
    const int scol = (lane & 3) * 8;     // shorts

#define QSTAGE(K0, AD, BD)                                                     \
    {                                                                          \
        GLOAD_LDS16(&xb[(size_t)(m0 + wid * 16 + srow) * CDIM + (K0) + scol],  \
                    (AD) + wid * 16 * 32);                                     \
        _Pragma("unroll") for (int c = 0; c < 2; c++)                          \
            GLOAD_LDS16(&wt[(size_t)(n0 + wid * 32 + c * 16 + srow) * CDIM + (K0) + scol], \
                        (BD) + (wid * 32 + c * 16) * 32);                      \
    }

#define QCOMPUTE(AS, BS)                                                       \
    {                                                                          \
        bf16x8 a[2], b[4];                                                     \
        _Pragma("unroll") for (int mt = 0; mt < 2; mt++)                       \
            a[mt] = *reinterpret_cast<const bf16x8*>(                          \
                (AS) + (wr + 16 * mt + li) * 32 + 8 * g);                      \
        _Pragma("unroll") for (int nt = 0; nt < 4; nt++)                       \
            b[nt] = *reinterpret_cast<const bf16x8*>(                          \
                (BS) + (wc + 16 * nt + li) * 32 + 8 * g);                      \
        _Pragma("unroll") for (int mt = 0; mt < 2; mt++)                       \
            _Pragma("unroll") for (int nt = 0; nt < 4; nt++)                   \
                acc[mt][nt] = __builtin_amdgcn_mfma_f32_16x16x32_bf16(         \
                    a[mt], b[nt], acc[mt][nt], 0, 0, 0);                       \
    }

    f32x4 acc[2][4];
    #pragma unroll
    for (int i = 0; i < 2; i++)
        #pragma unroll
        for (int j = 0; j < 4; j++) acc[i][j] = f32x4{0.f, 0.f, 0.f, 0.f};

    QSTAGE(0, A0, B0);
    __syncthreads();

    for (int j = 0; j < 12; ++j) {
        const int k0 = j * 64;
        QSTAGE(k0 + 32, A1, B1);
        QCOMPUTE(A0, B0);
        __syncthreads();
        if (j < 11) QSTAGE(k0 + 64, A0, B0);
        QCOMPUTE(A1, B1);
        __syncthreads();
    }

    #pragma unroll
    for (int mt = 0; mt < 2; mt++) {
        #pragma unroll
        for (int nt = 0; nt < 4; nt++) {
            int col  = n0 + wc + 16 * nt + li;
            int tsel = col / CDIM;
            int rem  = col - tsel * CDIM;
            int h_ = rem >> 6, d = rem & 63;
            float bv = bias[col];
            float sc = (tsel == 0) ? 0.125f : 1.0f;
            #pragma unroll
            for (int r = 0; r < 4; r++) {
                int m  = m0 + wr + 16 * mt + 4 * g + r;
                int b_ = m >> 10, s = m & 1023;
                unsigned short hv = f2bf((acc[mt][nt][r] + bv) * sc);
                if (tsel == 0)
                    qbuf[(((size_t)b_ * NHEAD + h_) * NSEQ + s) * HDIM + d] = hv;
                else if (tsel == 1)
                    kbuf[(((size_t)b_ * NHEAD + h_) * NSEQ + s) * HDIM + d] = hv;
                else
                    vtbuf[(((size_t)b_ * NHEAD + h_) * HDIM + d) * NSEQ + s] = hv;
            }
        }
    }
#undef QSTAGE
#undef QCOMPUTE
}

// ---------------------------------------------------------------------------
// Flash-style attention — EXACT round-10 structure (best measured: 46.4 us).
// ---------------------------------------------------------------------------
__global__ __launch_bounds__(256, 3) void attn_kernel(
    const unsigned short* __restrict__ qbuf,
    const unsigned short* __restrict__ kbuf,
    const unsigned short* __restrict__ vtbuf,
    const float* __restrict__ bias,     // [H,N,N]
    unsigned short* __restrict__ ybuf)  // [B,N,C] bf16
{
    __shared__ unsigned short Kl[2][64 * 64];  // [k][d] linear, source-swizzled
    __shared__ unsigned short Vl[2][64 * 64];  // V^T [d][k] linear, swizzled
    __shared__ unsigned short Ps[4][16][72];   // per-wave P: [q][k]

    const int tid  = threadIdx.x;
    const int lane = tid & 63;
    const int wid  = tid >> 6;
    const int g = lane >> 4, li = lane & 15;
    const int srow8 = lane >> 3;               // 0..7
    const int scs   = (lane & 7) ^ srow8;      // swizzled source slot (16B units)
    const int bh = blockIdx.y;
    const int b_ = bh / NHEAD, h_ = bh % NHEAD;
    const int qw = blockIdx.x * 64 + wid * 16;

    const unsigned short* qb = qbuf + (size_t)bh * NSEQ * HDIM;
    const unsigned short* kb = kbuf + (size_t)bh * NSEQ * HDIM;
    const unsigned short* vb = vtbuf + (size_t)bh * HDIM * NSEQ;
    const float* bb = bias + (size_t)h_ * NSEQ * NSEQ;

#define STAGE_KV(T, KL, VL)                                                    \
    {                                                                          \
        _Pragma("unroll") for (int i = 0; i < 2; i++) {                        \
            GLOAD_LDS16(kb + (size_t)((T) * 64 + wid * 16 + i * 8 + srow8) * HDIM + scs * 8, \
                        (KL) + (wid * 16 + i * 8) * 64);                       \
            GLOAD_LDS16(vb + (size_t)(wid * 16 + i * 8 + srow8) * NSEQ + (T) * 64 + scs * 8, \
                        (VL) + (wid * 16 + i * 8) * 64);                       \
        }                                                                      \
    }

#define COMPUTE_TILE(KS, VS, T)                                                \
    {                                                                          \
        float bv[4][4];                                                        \
        _Pragma("unroll") for (int kt = 0; kt < 4; kt++)                       \
            _Pragma("unroll") for (int r = 0; r < 4; r++)                      \
                bv[kt][r] = bb[(size_t)(qw + 4 * g + r) * NSEQ + (T) * 64 + 16 * kt + li]; \
        f32x4 sacc[4];                                                         \
        _Pragma("unroll") for (int kt = 0; kt < 4; kt++)                       \
            sacc[kt] = f32x4{0.f, 0.f, 0.f, 0.f};                              \
        _Pragma("unroll") for (int kt = 0; kt < 4; kt++)                       \
            _Pragma("unroll") for (int dd = 0; dd < 2; dd++) {                 \
                bf16x8 kf = *reinterpret_cast<const bf16x8*>(                  \
                    (KS) + (16 * kt + li) * 64 + (((4 * dd + g) ^ (li & 7)) * 8)); \
                sacc[kt] = __builtin_amdgcn_mfma_f32_16x16x32_bf16(qf[dd], kf, sacc[kt], 0, 0, 0); \
            }                                                                  \
        _Pragma("unroll") for (int kt = 0; kt < 4; kt++)                       \
            _Pragma("unroll") for (int r = 0; r < 4; r++) {                    \
                float pv = __expf(sacc[kt][r] + bv[kt][r]);                    \
                lpart[r] += pv;                                                \
                Ps[wid][4 * g + r][16 * kt + li] = f2bf(pv);                   \
            }                                                                  \
        _Pragma("unroll") for (int kk = 0; kk < 2; kk++) {                     \
            bf16x8 pf = *reinterpret_cast<const bf16x8*>(&Ps[wid][li][32 * kk + 8 * g]); \
            _Pragma("unroll") for (int dt = 0; dt < 4; dt++) {                 \
                bf16x8 vf = *reinterpret_cast<const bf16x8*>(                  \
                    (VS) + (16 * dt + li) * 64 + (((4 * kk + g) ^ (li & 7)) * 8)); \
                oacc[dt] = __builtin_amdgcn_mfma_f32_16x16x32_bf16(pf, vf, oacc[dt], 0, 0, 0); \
            }                                                                  \
        }                                                                      \
    }

    bf16x8 qf[2];
    #pragma unroll
    for (int dd = 0; dd < 2; dd++)
        qf[dd] = *reinterpret_cast<const bf16x8*>(&qb[(size_t)(qw + li) * HDIM + 32 * dd + 8 * g]);

    f32x4 oacc[4];
    #pragma unroll
    for (int dt = 0; dt < 4; dt++) oacc[dt] = f32x4{0.f, 0.f, 0.f, 0.f};
    float lpart[4] = {0.f, 0.f, 0.f, 0.f};

    STAGE_KV(0, Kl[0], Vl[0]);
    __syncthreads();

    for (int j = 0; j < 8; ++j) {
        const int tA = 2 * j;
        STAGE_KV(tA + 1, Kl[1], Vl[1]);
        COMPUTE_TILE(Kl[0], Vl[0], tA);
        __syncthreads();

        if (j < 7) STAGE_KV(tA + 2, Kl[0], Vl[0]);
        COMPUTE_TILE(Kl[1], Vl[1], tA + 1);
        __syncthreads();
    }

    float linv[4];
    #pragma unroll
    for (int r = 0; r < 4; r++) {
        float s = lpart[r];
        s += __shfl_xor(s, 1);
        s += __shfl_xor(s, 2);
        s += __shfl_xor(s, 4);
        s += __shfl_xor(s, 8);
        linv[r] = 1.f / s;
    }
    #pragma unroll
    for (int dt = 0; dt < 4; dt++)
        #pragma unroll
        for (int r = 0; r < 4; r++) {
            float o = oacc[dt][r] * linv[r];
            int sq = qw + 4 * g + r;
            ybuf[((size_t)b_ * NSEQ + sq) * CDIM + h_ * HDIM + 16 * dt + li] = f2bf(o);
        }
#undef STAGE_KV
#undef COMPUTE_TILE
}

// ---------------------------------------------------------------------------
// Proj GEMM (r16 variant): 64x128 tile, BK=32, async dbuf. Grid 384.
// ---------------------------------------------------------------------------
__global__ __launch_bounds__(256) void proj_gemm(
    const unsigned short* __restrict__ yb,   // [4096][768]
    const unsigned short* __restrict__ pwt,  // [768][768] (n,k)
    const float* __restrict__ bias, float* __restrict__ out)
{
    __shared__ unsigned short A0[64 * 32], A1[64 * 32];
    __shared__ unsigned short B0[128 * 32], B1[128 * 32];
    const int tid  = threadIdx.x;
    const int lane = tid & 63;
    const int wid  = tid >> 6;
    const int wr = (wid >> 1) * 32, wc = (wid & 1) * 64;
    const int g = lane >> 4, li = lane & 15;
    const int m0 = blockIdx.y * 64;
    const int n0 = blockIdx.x * 128;
    const int srow = lane >> 2;
    const int scol = (lane & 3) * 8;

#define PSTAGE(K0, AD, BD)                                                     \
    {                                                                          \
        GLOAD_LDS16(&yb[(size_t)(m0 + wid * 16 + srow) * CDIM + (K0) + scol],  \
                    (AD) + wid * 16 * 32);                                     \
        _Pragma("unroll") for (int c = 0; c < 2; c++)                          \
            GLOAD_LDS16(&pwt[(size_t)(n0 + wid * 32 + c * 16 + srow) * CDIM + (K0) + scol], \
                        (BD) + (wid * 32 + c * 16) * 32);                      \
    }

#define PCOMPUTE(AS, BS)                                                       \
    {                                                                          \
        bf16x8 a[2], b[4];                                                     \
        _Pragma("unroll") for (int mt = 0; mt < 2; mt++)                       \
            a[mt] = *reinterpret_cast<const bf16x8*>(                          \
                (AS) + (wr + 16 * mt + li) * 32 + 8 * g);                      \
        _Pragma("unroll") for (int nt = 0; nt < 4; nt++)                       \
            b[nt] = *reinterpret_cast<const bf16x8*>(                          \
                (BS) + (wc + 16 * nt + li) * 32 + 8 * g);                      \
        _Pragma("unroll") for (int mt = 0; mt < 2; mt++)                       \
            _Pragma("unroll") for (int nt = 0; nt < 4; nt++)                   \
                acc[mt][nt] = __builtin_amdgcn_mfma_f32_16x16x32_bf16(         \
                    a[mt], b[nt], acc[mt][nt], 0, 0, 0);                       \
    }

    f32x4 acc[2][4];
    #pragma unroll
    for (int i = 0; i < 2; i++)
        #pragma unroll
        for (int j = 0; j < 4; j++) acc[i][j] = f32x4{0.f, 0.f, 0.f, 0.f};

    PSTAGE(0, A0, B0);
    __syncthreads();

    for (int j = 0; j < 12; ++j) {
        const int k0 = j * 64;
        PSTAGE(k0 + 32, A1, B1);
        PCOMPUTE(A0, B0);
        __syncthreads();
        if (j < 11) PSTAGE(k0 + 64, A0, B0);
        PCOMPUTE(A1, B1);
        __syncthreads();
    }

    #pragma unroll
    for (int mt = 0; mt < 2; mt++)
        #pragma unroll
        for (int nt = 0; nt < 4; nt++) {
            int col = n0 + wc + 16 * nt + li;
            float bv = bias[col];
            #pragma unroll
            for (int r = 0; r < 4; r++) {
                int m = m0 + wr + 16 * mt + 4 * g + r;
                out[(size_t)m * CDIM + col] = acc[mt][nt][r] + bv;
            }
        }
#undef PSTAGE
#undef PCOMPUTE
}

extern "C" void kernel_launch(void* const* d_in, const int* in_sizes, int n_in,
                              void* d_out, int out_size, void* d_ws, size_t ws_size,
                              hipStream_t stream) {
    const float* x         = (const float*)d_in[0];
    const float* attn_bias = (const float*)d_in[1];
    const float* qkv_w     = (const float*)d_in[2];
    const float* qkv_b     = (const float*)d_in[3];
    const float* proj_w    = (const float*)d_in[4];
    const float* proj_b    = (const float*)d_in[5];
    float* out = (float*)d_out;

    const size_t per = (size_t)BATCH * NHEAD * NSEQ * HDIM;  // 3,145,728
    unsigned short* qbuf  = (unsigned short*)d_ws;
    unsigned short* kbuf  = qbuf + per;
    unsigned short* vtbuf = kbuf + per;
    unsigned short* xb    = vtbuf + per;
    unsigned short* qwt   = xb + per;                    // [2304][768]
    unsigned short* pwt   = qwt + (size_t)QKVN * CDIM;   // [768][768]
    unsigned short* ybuf  = xb;  // x dead after qkv_gemm

    prep_kernel<<<NB_X + NB_QW + NB_PW, 256, 0, stream>>>(
        x, xb, qkv_w, qwt, proj_w, pwt);

    qkv_gemm<<<dim3(QKVN / 128, MTOT / 64), 256, 0, stream>>>(
        xb, qwt, qkv_b, qbuf, kbuf, vtbuf);
    attn_kernel<<<dim3(NSEQ / 64, BATCH * NHEAD), 256, 0, stream>>>(
        qbuf, kbuf, vtbuf, attn_bias, ybuf);
    proj_gemm<<<dim3(CDIM / 128, MTOT / 64), 256, 0, stream>>>(
        ybuf, pwt, proj_b, out);
}

// Round 19
// 100.828 us; speedup vs baseline: 1.0606x; 1.0164x over previous
//
#include <hip/hip_runtime.h>
#include <hip/hip_bf16.h>

// Problem constants
constexpr int BATCH = 4;
constexpr int NSEQ  = 1024;
constexpr int CDIM  = 768;
constexpr int NHEAD = 12;
constexpr int HDIM  = 64;
constexpr int MTOT  = BATCH * NSEQ;   // 4096
constexpr int QKVN  = 3 * CDIM;       // 2304

typedef __bf16 bf16x8 __attribute__((ext_vector_type(8)));
typedef float  f32x4  __attribute__((ext_vector_type(4)));

__device__ __forceinline__ unsigned short f2bf(float f) {
    unsigned u = __builtin_bit_cast(unsigned, f);
    unsigned r = u + 0x7FFFu + ((u >> 16) & 1u);   // RNE
    return (unsigned short)(r >> 16);
}

#define GLOAD_LDS16(gp, lp)                                                    \
    __builtin_amdgcn_global_load_lds(                                          \
        (const __attribute__((address_space(1))) void*)(gp),                   \
        (__attribute__((address_space(3))) void*)(lp), 16, 0, 0)

// ---------------------------------------------------------------------------
// Fused prologue: ONE kernel does all three conversions (r18 win, -3.5us).
// ---------------------------------------------------------------------------
constexpr int NB_X  = MTOT * CDIM / 4 / 256;       // 3072
constexpr int NB_QW = (QKVN / 32) * (CDIM / 32);   // 1728
constexpr int NB_PW = (CDIM / 32) * (CDIM / 32);   // 576

__device__ __forceinline__ void tcvt_tile(
    const float* __restrict__ in, unsigned short* __restrict__ out,
    int R, int C, int c0, int r0, int tid)
{
    __shared__ unsigned short t[32][33];
    const int tc = tid & 31, tr = tid >> 5;  // tr 0..7
    #pragma unroll
    for (int i = 0; i < 4; i++)
        t[tc][tr + 8 * i] = f2bf(in[(size_t)(r0 + tr + 8 * i) * C + c0 + tc]);
    __syncthreads();
    #pragma unroll
    for (int i = 0; i < 4; i++)
        out[(size_t)(c0 + tr + 8 * i) * R + r0 + tc] = t[tr + 8 * i][tc];
}

__global__ __launch_bounds__(256) void prep_kernel(
    const float* __restrict__ x,      unsigned short* __restrict__ xb,
    const float* __restrict__ qkv_w,  unsigned short* __restrict__ qwt,
    const float* __restrict__ proj_w, unsigned short* __restrict__ pwt)
{
    const int bid = blockIdx.x;
    const int tid = threadIdx.x;
    if (bid < NB_X) {
        int i = bid * 256 + tid;
        float4 a = reinterpret_cast<const float4*>(x)[i];
        ushort4 h;
        h.x = f2bf(a.x); h.y = f2bf(a.y); h.z = f2bf(a.z); h.w = f2bf(a.w);
        reinterpret_cast<ushort4*>(xb)[i] = h;
    } else if (bid < NB_X + NB_QW) {
        int t = bid - NB_X;
        tcvt_tile(qkv_w, qwt, CDIM, QKVN, (t % (QKVN / 32)) * 32,
                  (t / (QKVN / 32)) * 32, tid);
    } else {
        int t = bid - NB_X - NB_QW;
        tcvt_tile(proj_w, pwt, CDIM, CDIM, (t % (CDIM / 32)) * 32,
                  (t / (CDIM / 32)) * 32, tid);
    }
}

// ---------------------------------------------------------------------------
// QKV GEMM: r16 geometry (64x128 tile, BK=32, async dbuf, grid 1152) +
// r17-derived 2-way LDS swizzle: store slot s of row r at s^((r>>1)&3)
// (source col ((lane&3)^((lane>>3)&3))*8 — base rows are multiples of 16 so
// (r>>1)&3 reduces to (lane>>3)&3), read slot g^((li>>1)&3). 8-way -> 2-way
// (free per m136). Conflicts predicted 2.65M -> ~0.
// ---------------------------------------------------------------------------
__global__ __launch_bounds__(256) void qkv_gemm(
    const unsigned short* __restrict__ xb,   // [4096][768]
    const unsigned short* __restrict__ wt,   // [2304][768]
    const float* __restrict__ bias,
    unsigned short* __restrict__ qbuf, unsigned short* __restrict__ kbuf,
    unsigned short* __restrict__ vtbuf)
{
    __shared__ unsigned short A0[64 * 32], A1[64 * 32];
    __shared__ unsigned short B0[128 * 32], B1[128 * 32];
    const int tid  = threadIdx.x;
    const int lane = tid & 63;
    const int wid  = tid >> 6;
    const int wr = (wid >> 1) * 32, wc = (wid & 1) * 64;
    const int g = lane >> 4, li = lane & 15;
    const int m0 = blockIdx.y * 64;
    const int n0 = blockIdx.x * 128;
    const int srow = lane >> 2;                               // 0..15
    const int scol = ((lane & 3) ^ ((lane >> 3) & 3)) * 8;    // swizzled src col
    const int rsl  = (g ^ ((li >> 1) & 3)) * 8;               // swizzled read col

#define QSTAGE(K0, AD, BD)                                                     \
    {                                                                          \
        GLOAD_LDS16(&xb[(size_t)(m0 + wid * 16 + srow) * CDIM + (K0) + scol],  \
                    (AD) + wid * 16 * 32);                                     \
        _Pragma("unroll") for (int c = 0; c < 2; c++)                          \
            GLOAD_LDS16(&wt[(size_t)(n0 + wid * 32 + c * 16 + srow) * CDIM + (K0) + scol], \
                        (BD) + (wid * 32 + c * 16) * 32);                      \
    }

#define QCOMPUTE(AS, BS)                                                       \
    {                                                                          \
        bf16x8 a[2], b[4];                                                     \
        _Pragma("unroll") for (int mt = 0; mt < 2; mt++)                       \
            a[mt] = *reinterpret_cast<const bf16x8*>(                          \
                (AS) + (wr + 16 * mt + li) * 32 + rsl);                        \
        _Pragma("unroll") for (int nt = 0; nt < 4; nt++)                       \
            b[nt] = *reinterpret_cast<const bf16x8*>(                          \
                (BS) + (wc + 16 * nt + li) * 32 + rsl);                        \
        _Pragma("unroll") for (int mt = 0; mt < 2; mt++)                       \
            _Pragma("unroll") for (int nt = 0; nt < 4; nt++)                   \
                acc[mt][nt] = __builtin_amdgcn_mfma_f32_16x16x32_bf16(         \
                    a[mt], b[nt], acc[mt][nt], 0, 0, 0);                       \
    }

    f32x4 acc[2][4];
    #pragma unroll
    for (int i = 0; i < 2; i++)
        #pragma unroll
        for (int j = 0; j < 4; j++) acc[i][j] = f32x4{0.f, 0.f, 0.f, 0.f};

    QSTAGE(0, A0, B0);
    __syncthreads();

    for (int j = 0; j < 12; ++j) {
        const int k0 = j * 64;
        QSTAGE(k0 + 32, A1, B1);
        QCOMPUTE(A0, B0);
        __syncthreads();
        if (j < 11) QSTAGE(k0 + 64, A0, B0);
        QCOMPUTE(A1, B1);
        __syncthreads();
    }

    #pragma unroll
    for (int mt = 0; mt < 2; mt++) {
        #pragma unroll
        for (int nt = 0; nt < 4; nt++) {
            int col  = n0 + wc + 16 * nt + li;
            int tsel = col / CDIM;
            int rem  = col - tsel * CDIM;
            int h_ = rem >> 6, d = rem & 63;
            float bv = bias[col];
            float sc = (tsel == 0) ? 0.125f : 1.0f;
            #pragma unroll
            for (int r = 0; r < 4; r++) {
                int m  = m0 + wr + 16 * mt + 4 * g + r;
                int b_ = m >> 10, s = m & 1023;
                unsigned short hv = f2bf((acc[mt][nt][r] + bv) * sc);
                if (tsel == 0)
                    qbuf[(((size_t)b_ * NHEAD + h_) * NSEQ + s) * HDIM + d] = hv;
                else if (tsel == 1)
                    kbuf[(((size_t)b_ * NHEAD + h_) * NSEQ + s) * HDIM + d] = hv;
                else
                    vtbuf[(((size_t)b_ * NHEAD + h_) * HDIM + d) * NSEQ + s] = hv;
            }
        }
    }
#undef QSTAGE
#undef QCOMPUTE
}

// ---------------------------------------------------------------------------
// Flash-style attention — EXACT round-10 structure (best measured: 46.4 us).
// ---------------------------------------------------------------------------
__global__ __launch_bounds__(256, 3) void attn_kernel(
    const unsigned short* __restrict__ qbuf,
    const unsigned short* __restrict__ kbuf,
    const unsigned short* __restrict__ vtbuf,
    const float* __restrict__ bias,     // [H,N,N]
    unsigned short* __restrict__ ybuf)  // [B,N,C] bf16
{
    __shared__ unsigned short Kl[2][64 * 64];  // [k][d] linear, source-swizzled
    __shared__ unsigned short Vl[2][64 * 64];  // V^T [d][k] linear, swizzled
    __shared__ unsigned short Ps[4][16][72];   // per-wave P: [q][k]

    const int tid  = threadIdx.x;
    const int lane = tid & 63;
    const int wid  = tid >> 6;
    const int g = lane >> 4, li = lane & 15;
    const int srow8 = lane >> 3;               // 0..7
    const int scs   = (lane & 7) ^ srow8;      // swizzled source slot (16B units)
    const int bh = blockIdx.y;
    const int b_ = bh / NHEAD, h_ = bh % NHEAD;
    const int qw = blockIdx.x * 64 + wid * 16;

    const unsigned short* qb = qbuf + (size_t)bh * NSEQ * HDIM;
    const unsigned short* kb = kbuf + (size_t)bh * NSEQ * HDIM;
    const unsigned short* vb = vtbuf + (size_t)bh * HDIM * NSEQ;
    const float* bb = bias + (size_t)h_ * NSEQ * NSEQ;

#define STAGE_KV(T, KL, VL)                                                    \
    {                                                                          \
        _Pragma("unroll") for (int i = 0; i < 2; i++) {                        \
            GLOAD_LDS16(kb + (size_t)((T) * 64 + wid * 16 + i * 8 + srow8) * HDIM + scs * 8, \
                        (KL) + (wid * 16 + i * 8) * 64);                       \
            GLOAD_LDS16(vb + (size_t)(wid * 16 + i * 8 + srow8) * NSEQ + (T) * 64 + scs * 8, \
                        (VL) + (wid * 16 + i * 8) * 64);                       \
        }                                                                      \
    }

#define COMPUTE_TILE(KS, VS, T)                                                \
    {                                                                          \
        float bv[4][4];                                                        \
        _Pragma("unroll") for (int kt = 0; kt < 4; kt++)                       \
            _Pragma("unroll") for (int r = 0; r < 4; r++)                      \
                bv[kt][r] = bb[(size_t)(qw + 4 * g + r) * NSEQ + (T) * 64 + 16 * kt + li]; \
        f32x4 sacc[4];                                                         \
        _Pragma("unroll") for (int kt = 0; kt < 4; kt++)                       \
            sacc[kt] = f32x4{0.f, 0.f, 0.f, 0.f};                              \
        _Pragma("unroll") for (int kt = 0; kt < 4; kt++)                       \
            _Pragma("unroll") for (int dd = 0; dd < 2; dd++) {                 \
                bf16x8 kf = *reinterpret_cast<const bf16x8*>(                  \
                    (KS) + (16 * kt + li) * 64 + (((4 * dd + g) ^ (li & 7)) * 8)); \
                sacc[kt] = __builtin_amdgcn_mfma_f32_16x16x32_bf16(qf[dd], kf, sacc[kt], 0, 0, 0); \
            }                                                                  \
        _Pragma("unroll") for (int kt = 0; kt < 4; kt++)                       \
            _Pragma("unroll") for (int r = 0; r < 4; r++) {                    \
                float pv = __expf(sacc[kt][r] + bv[kt][r]);                    \
                lpart[r] += pv;                                                \
                Ps[wid][4 * g + r][16 * kt + li] = f2bf(pv);                   \
            }                                                                  \
        _Pragma("unroll") for (int kk = 0; kk < 2; kk++) {                     \
            bf16x8 pf = *reinterpret_cast<const bf16x8*>(&Ps[wid][li][32 * kk + 8 * g]); \
            _Pragma("unroll") for (int dt = 0; dt < 4; dt++) {                 \
                bf16x8 vf = *reinterpret_cast<const bf16x8*>(                  \
                    (VS) + (16 * dt + li) * 64 + (((4 * kk + g) ^ (li & 7)) * 8)); \
                oacc[dt] = __builtin_amdgcn_mfma_f32_16x16x32_bf16(pf, vf, oacc[dt], 0, 0, 0); \
            }                                                                  \
        }                                                                      \
    }

    bf16x8 qf[2];
    #pragma unroll
    for (int dd = 0; dd < 2; dd++)
        qf[dd] = *reinterpret_cast<const bf16x8*>(&qb[(size_t)(qw + li) * HDIM + 32 * dd + 8 * g]);

    f32x4 oacc[4];
    #pragma unroll
    for (int dt = 0; dt < 4; dt++) oacc[dt] = f32x4{0.f, 0.f, 0.f, 0.f};
    float lpart[4] = {0.f, 0.f, 0.f, 0.f};

    STAGE_KV(0, Kl[0], Vl[0]);
    __syncthreads();

    for (int j = 0; j < 8; ++j) {
        const int tA = 2 * j;
        STAGE_KV(tA + 1, Kl[1], Vl[1]);
        COMPUTE_TILE(Kl[0], Vl[0], tA);
        __syncthreads();

        if (j < 7) STAGE_KV(tA + 2, Kl[0], Vl[0]);
        COMPUTE_TILE(Kl[1], Vl[1], tA + 1);
        __syncthreads();
    }

    float linv[4];
    #pragma unroll
    for (int r = 0; r < 4; r++) {
        float s = lpart[r];
        s += __shfl_xor(s, 1);
        s += __shfl_xor(s, 2);
        s += __shfl_xor(s, 4);
        s += __shfl_xor(s, 8);
        linv[r] = 1.f / s;
    }
    #pragma unroll
    for (int dt = 0; dt < 4; dt++)
        #pragma unroll
        for (int r = 0; r < 4; r++) {
            float o = oacc[dt][r] * linv[r];
            int sq = qw + 4 * g + r;
            ybuf[((size_t)b_ * NSEQ + sq) * CDIM + h_ * HDIM + 16 * dt + li] = f2bf(o);
        }
#undef STAGE_KV
#undef COMPUTE_TILE
}

// ---------------------------------------------------------------------------
// Proj GEMM: r16 geometry + same 2-way swizzle as qkv_gemm.
// ---------------------------------------------------------------------------
__global__ __launch_bounds__(256) void proj_gemm(
    const unsigned short* __restrict__ yb,   // [4096][768]
    const unsigned short* __restrict__ pwt,  // [768][768] (n,k)
    const float* __restrict__ bias, float* __restrict__ out)
{
    __shared__ unsigned short A0[64 * 32], A1[64 * 32];
    __shared__ unsigned short B0[128 * 32], B1[128 * 32];
    const int tid  = threadIdx.x;
    const int lane = tid & 63;
    const int wid  = tid >> 6;
    const int wr = (wid >> 1) * 32, wc = (wid & 1) * 64;
    const int g = lane >> 4, li = lane & 15;
    const int m0 = blockIdx.y * 64;
    const int n0 = blockIdx.x * 128;
    const int srow = lane >> 2;
    const int scol = ((lane & 3) ^ ((lane >> 3) & 3)) * 8;
    const int rsl  = (g ^ ((li >> 1) & 3)) * 8;

#define PSTAGE(K0, AD, BD)                                                     \
    {                                                                          \
        GLOAD_LDS16(&yb[(size_t)(m0 + wid * 16 + srow) * CDIM + (K0) + scol],  \
                    (AD) + wid * 16 * 32);                                     \
        _Pragma("unroll") for (int c = 0; c < 2; c++)                          \
            GLOAD_LDS16(&pwt[(size_t)(n0 + wid * 32 + c * 16 + srow) * CDIM + (K0) + scol], \
                        (BD) + (wid * 32 + c * 16) * 32);                      \
    }

#define PCOMPUTE(AS, BS)                                                       \
    {                                                                          \
        bf16x8 a[2], b[4];                                                     \
        _Pragma("unroll") for (int mt = 0; mt < 2; mt++)                       \
            a[mt] = *reinterpret_cast<const bf16x8*>(                          \
                (AS) + (wr + 16 * mt + li) * 32 + rsl);                        \
        _Pragma("unroll") for (int nt = 0; nt < 4; nt++)                       \
            b[nt] = *reinterpret_cast<const bf16x8*>(                          \
                (BS) + (wc + 16 * nt + li) * 32 + rsl);                        \
        _Pragma("unroll") for (int mt = 0; mt < 2; mt++)                       \
            _Pragma("unroll") for (int nt = 0; nt < 4; nt++)                   \
                acc[mt][nt] = __builtin_amdgcn_mfma_f32_16x16x32_bf16(         \
                    a[mt], b[nt], acc[mt][nt], 0, 0, 0);                       \
    }

    f32x4 acc[2][4];
    #pragma unroll
    for (int i = 0; i < 2; i++)
        #pragma unroll
        for (int j = 0; j < 4; j++) acc[i][j] = f32x4{0.f, 0.f, 0.f, 0.f};

    PSTAGE(0, A0, B0);
    __syncthreads();

    for (int j = 0; j < 12; ++j) {
        const int k0 = j * 64;
        PSTAGE(k0 + 32, A1, B1);
        PCOMPUTE(A0, B0);
        __syncthreads();
        if (j < 11) PSTAGE(k0 + 64, A0, B0);
        PCOMPUTE(A1, B1);
        __syncthreads();
    }

    #pragma unroll
    for (int mt = 0; mt < 2; mt++)
        #pragma unroll
        for (int nt = 0; nt < 4; nt++) {
            int col = n0 + wc + 16 * nt + li;
            float bv = bias[col];
            #pragma unroll
            for (int r = 0; r < 4; r++) {
                int m = m0 + wr + 16 * mt + 4 * g + r;
                out[(size_t)m * CDIM + col] = acc[mt][nt][r] + bv;
            }
        }
#undef PSTAGE
#undef PCOMPUTE
}

extern "C" void kernel_launch(void* const* d_in, const int* in_sizes, int n_in,
                              void* d_out, int out_size, void* d_ws, size_t ws_size,
                              hipStream_t stream) {
    const float* x         = (const float*)d_in[0];
    const float* attn_bias = (const float*)d_in[1];
    const float* qkv_w     = (const float*)d_in[2];
    const float* qkv_b     = (const float*)d_in[3];
    const float* proj_w    = (const float*)d_in[4];
    const float* proj_b    = (const float*)d_in[5];
    float* out = (float*)d_out;

    const size_t per = (size_t)BATCH * NHEAD * NSEQ * HDIM;  // 3,145,728
    unsigned short* qbuf  = (unsigned short*)d_ws;
    unsigned short* kbuf  = qbuf + per;
    unsigned short* vtbuf = kbuf + per;
    unsigned short* xb    = vtbuf + per;
    unsigned short* qwt   = xb + per;                    // [2304][768]
    unsigned short* pwt   = qwt + (size_t)QKVN * CDIM;   // [768][768]
    unsigned short* ybuf  = xb;  // x dead after qkv_gemm

    prep_kernel<<<NB_X + NB_QW + NB_PW, 256, 0, stream>>>(
        x, xb, qkv_w, qwt, proj_w, pwt);

    qkv_gemm<<<dim3(QKVN / 128, MTOT / 64), 256, 0, stream>>>(
        xb, qwt, qkv_b, qbuf, kbuf, vtbuf);
    attn_kernel<<<dim3(NSEQ / 64, BATCH * NHEAD), 256, 0, stream>>>(
        qbuf, kbuf, vtbuf, attn_bias, ybuf);
    proj_gemm<<<dim3(CDIM / 128, MTOT / 64), 256, 0, stream>>>(
        ybuf, pwt, proj_b, out);
}

// Round 20
// 99.012 us; speedup vs baseline: 1.0801x; 1.0183x over previous
//
#include <hip/hip_runtime.h>
#include <hip/hip_bf16.h>

// Problem constants
constexpr int BATCH = 4;
constexpr int NSEQ  = 1024;
constexpr int CDIM  = 768;
constexpr int NHEAD = 12;
constexpr int HDIM  = 64;
constexpr int MTOT  = BATCH * NSEQ;   // 4096
constexpr int QKVN  = 3 * CDIM;       // 2304

typedef __bf16 bf16x8 __attribute__((ext_vector_type(8)));
typedef float  f32x4  __attribute__((ext_vector_type(4)));

__device__ __forceinline__ unsigned short f2bf(float f) {
    unsigned u = __builtin_bit_cast(unsigned, f);
    unsigned r = u + 0x7FFFu + ((u >> 16) & 1u);   // RNE
    return (unsigned short)(r >> 16);
}

#define GLOAD_LDS16(gp, lp)                                                    \
    __builtin_amdgcn_global_load_lds(                                          \
        (const __attribute__((address_space(1))) void*)(gp),                   \
        (__attribute__((address_space(3))) void*)(lp), 16, 0, 0)

// ---------------------------------------------------------------------------
// Fused prologue: ONE kernel does all three conversions (r18 win).
// ---------------------------------------------------------------------------
constexpr int NB_X  = MTOT * CDIM / 4 / 256;       // 3072
constexpr int NB_QW = (QKVN / 32) * (CDIM / 32);   // 1728
constexpr int NB_PW = (CDIM / 32) * (CDIM / 32);   // 576

__device__ __forceinline__ void tcvt_tile(
    const float* __restrict__ in, unsigned short* __restrict__ out,
    int R, int C, int c0, int r0, int tid)
{
    __shared__ unsigned short t[32][33];
    const int tc = tid & 31, tr = tid >> 5;  // tr 0..7
    #pragma unroll
    for (int i = 0; i < 4; i++)
        t[tc][tr + 8 * i] = f2bf(in[(size_t)(r0 + tr + 8 * i) * C + c0 + tc]);
    __syncthreads();
    #pragma unroll
    for (int i = 0; i < 4; i++)
        out[(size_t)(c0 + tr + 8 * i) * R + r0 + tc] = t[tr + 8 * i][tc];
}

__global__ __launch_bounds__(256) void prep_kernel(
    const float* __restrict__ x,      unsigned short* __restrict__ xb,
    const float* __restrict__ qkv_w,  unsigned short* __restrict__ qwt,
    const float* __restrict__ proj_w, unsigned short* __restrict__ pwt)
{
    const int bid = blockIdx.x;
    const int tid = threadIdx.x;
    if (bid < NB_X) {
        int i = bid * 256 + tid;
        float4 a = reinterpret_cast<const float4*>(x)[i];
        ushort4 h;
        h.x = f2bf(a.x); h.y = f2bf(a.y); h.z = f2bf(a.z); h.w = f2bf(a.w);
        reinterpret_cast<ushort4*>(xb)[i] = h;
    } else if (bid < NB_X + NB_QW) {
        int t = bid - NB_X;
        tcvt_tile(qkv_w, qwt, CDIM, QKVN, (t % (QKVN / 32)) * 32,
                  (t / (QKVN / 32)) * 32, tid);
    } else {
        int t = bid - NB_X - NB_QW;
        tcvt_tile(proj_w, pwt, CDIM, CDIM, (t % (CDIM / 32)) * 32,
                  (t / (CDIM / 32)) * 32, tid);
    }
}

// ---------------------------------------------------------------------------
// QKV GEMM: r19 geometry (64x128, BK=32, swizzled LDS) upgraded to a 3-deep
// pipeline with COUNTED vmcnt (T4): step s computes buf s%3 while the stage
// for s+2 stays in flight ACROSS the barrier. Raw s_barrier (no vmcnt(0)
// drain); per-wave `s_waitcnt vmcnt(3)` drains only stage(s+1) (each wave's
// 3 loads/stage). sched_barrier(0) after waitcnt per rule #18. Buffers
// statically named (rule #20): 8 iters x 3 phases. LDS 36KB -> 4 blocks/CU.
// ---------------------------------------------------------------------------
__global__ __launch_bounds__(256) void qkv_gemm(
    const unsigned short* __restrict__ xb,   // [4096][768]
    const unsigned short* __restrict__ wt,   // [2304][768]
    const float* __restrict__ bias,
    unsigned short* __restrict__ qbuf, unsigned short* __restrict__ kbuf,
    unsigned short* __restrict__ vtbuf)
{
    __shared__ unsigned short A0[64 * 32], A1[64 * 32], A2[64 * 32];
    __shared__ unsigned short B0[128 * 32], B1[128 * 32], B2[128 * 32];
    const int tid  = threadIdx.x;
    const int lane = tid & 63;
    const int wid  = tid >> 6;
    const int wr = (wid >> 1) * 32, wc = (wid & 1) * 64;
    const int g = lane >> 4, li = lane & 15;
    const int m0 = blockIdx.y * 64;
    const int n0 = blockIdx.x * 128;
    const int srow = lane >> 2;                               // 0..15
    const int scol = ((lane & 3) ^ ((lane >> 3) & 3)) * 8;    // swizzled src col
    const int rsl  = (g ^ ((li >> 1) & 3)) * 8;               // swizzled read col

    // 3 global_load_lds per wave per stage
#define QSTAGE(K0, AD, BD)                                                     \
    {                                                                          \
        GLOAD_LDS16(&xb[(size_t)(m0 + wid * 16 + srow) * CDIM + (K0) + scol],  \
                    (AD) + wid * 16 * 32);                                     \
        _Pragma("unroll") for (int c = 0; c < 2; c++)                          \
            GLOAD_LDS16(&wt[(size_t)(n0 + wid * 32 + c * 16 + srow) * CDIM + (K0) + scol], \
                        (BD) + (wid * 32 + c * 16) * 32);                      \
    }

#define QCOMPUTE(AS, BS)                                                       \
    {                                                                          \
        bf16x8 a[2], b[4];                                                     \
        _Pragma("unroll") for (int mt = 0; mt < 2; mt++)                       \
            a[mt] = *reinterpret_cast<const bf16x8*>(                          \
                (AS) + (wr + 16 * mt + li) * 32 + rsl);                        \
        _Pragma("unroll") for (int nt = 0; nt < 4; nt++)                       \
            b[nt] = *reinterpret_cast<const bf16x8*>(                          \
                (BS) + (wc + 16 * nt + li) * 32 + rsl);                        \
        _Pragma("unroll") for (int mt = 0; mt < 2; mt++)                       \
            _Pragma("unroll") for (int nt = 0; nt < 4; nt++)                   \
                acc[mt][nt] = __builtin_amdgcn_mfma_f32_16x16x32_bf16(         \
                    a[mt], b[nt], acc[mt][nt], 0, 0, 0);                       \
    }

    // drain all but the newest stage (3 loads in flight), publish LDS
#define WAITBAR3()                                                             \
    {                                                                          \
        asm volatile("s_waitcnt vmcnt(3)" ::: "memory");                       \
        __builtin_amdgcn_sched_barrier(0);                                     \
        __builtin_amdgcn_s_barrier();                                          \
        __builtin_amdgcn_sched_barrier(0);                                     \
    }
#define WAITBAR0()                                                             \
    {                                                                          \
        asm volatile("s_waitcnt vmcnt(0)" ::: "memory");                       \
        __builtin_amdgcn_sched_barrier(0);                                     \
        __builtin_amdgcn_s_barrier();                                          \
        __builtin_amdgcn_sched_barrier(0);                                     \
    }

    f32x4 acc[2][4];
    #pragma unroll
    for (int i = 0; i < 2; i++)
        #pragma unroll
        for (int j = 0; j < 4; j++) acc[i][j] = f32x4{0.f, 0.f, 0.f, 0.f};

    // prologue: stages 0,1 in flight; drain stage0, publish
    QSTAGE(0, A0, B0);
    QSTAGE(32, A1, B1);
    WAITBAR3();

    // 24 K-steps = 8 iters x 3 statically-named phases
    for (int j = 0; j < 8; ++j) {
        const int k0 = j * 96;
        // phase A: compute buf0 (step 3j), stage step 3j+2 -> buf2
        QSTAGE(k0 + 64, A2, B2);
        QCOMPUTE(A0, B0);
        WAITBAR3();
        // phase B: compute buf1 (step 3j+1), stage step 3j+3 -> buf0
        if (j < 7) {
            QSTAGE(k0 + 96, A0, B0);
            QCOMPUTE(A1, B1);
            WAITBAR3();
            // phase C: compute buf2 (step 3j+2), stage 3j+4 -> buf1
            QSTAGE(k0 + 128, A1, B1);
            QCOMPUTE(A2, B2);
            WAITBAR3();
        } else {
            // steps 22,23: no more stages; drain everything
            QCOMPUTE(A1, B1);
            WAITBAR0();
            QCOMPUTE(A2, B2);
            // no barrier needed after last compute
        }
    }

    #pragma unroll
    for (int mt = 0; mt < 2; mt++) {
        #pragma unroll
        for (int nt = 0; nt < 4; nt++) {
            int col  = n0 + wc + 16 * nt + li;
            int tsel = col / CDIM;
            int rem  = col - tsel * CDIM;
            int h_ = rem >> 6, d = rem & 63;
            float bv = bias[col];
            float sc = (tsel == 0) ? 0.125f : 1.0f;
            #pragma unroll
            for (int r = 0; r < 4; r++) {
                int m  = m0 + wr + 16 * mt + 4 * g + r;
                int b_ = m >> 10, s = m & 1023;
                unsigned short hv = f2bf((acc[mt][nt][r] + bv) * sc);
                if (tsel == 0)
                    qbuf[(((size_t)b_ * NHEAD + h_) * NSEQ + s) * HDIM + d] = hv;
                else if (tsel == 1)
                    kbuf[(((size_t)b_ * NHEAD + h_) * NSEQ + s) * HDIM + d] = hv;
                else
                    vtbuf[(((size_t)b_ * NHEAD + h_) * HDIM + d) * NSEQ + s] = hv;
            }
        }
    }
#undef QSTAGE
#undef QCOMPUTE
#undef WAITBAR3
#undef WAITBAR0
}

// ---------------------------------------------------------------------------
// Flash-style attention — EXACT round-10 structure (best measured: 46.4 us).
// ---------------------------------------------------------------------------
__global__ __launch_bounds__(256, 3) void attn_kernel(
    const unsigned short* __restrict__ qbuf,
    const unsigned short* __restrict__ kbuf,
    const unsigned short* __restrict__ vtbuf,
    const float* __restrict__ bias,     // [H,N,N]
    unsigned short* __restrict__ ybuf)  // [B,N,C] bf16
{
    __shared__ unsigned short Kl[2][64 * 64];  // [k][d] linear, source-swizzled
    __shared__ unsigned short Vl[2][64 * 64];  // V^T [d][k] linear, swizzled
    __shared__ unsigned short Ps[4][16][72];   // per-wave P: [q][k]

    const int tid  = threadIdx.x;
    const int lane = tid & 63;
    const int wid  = tid >> 6;
    const int g = lane >> 4, li = lane & 15;
    const int srow8 = lane >> 3;               // 0..7
    const int scs   = (lane & 7) ^ srow8;      // swizzled source slot (16B units)
    const int bh = blockIdx.y;
    const int b_ = bh / NHEAD, h_ = bh % NHEAD;
    const int qw = blockIdx.x * 64 + wid * 16;

    const unsigned short* qb = qbuf + (size_t)bh * NSEQ * HDIM;
    const unsigned short* kb = kbuf + (size_t)bh * NSEQ * HDIM;
    const unsigned short* vb = vtbuf + (size_t)bh * HDIM * NSEQ;
    const float* bb = bias + (size_t)h_ * NSEQ * NSEQ;

#define STAGE_KV(T, KL, VL)                                                    \
    {                                                                          \
        _Pragma("unroll") for (int i = 0; i < 2; i++) {                        \
            GLOAD_LDS16(kb + (size_t)((T) * 64 + wid * 16 + i * 8 + srow8) * HDIM + scs * 8, \
                        (KL) + (wid * 16 + i * 8) * 64);                       \
            GLOAD_LDS16(vb + (size_t)(wid * 16 + i * 8 + srow8) * NSEQ + (T) * 64 + scs * 8, \
                        (VL) + (wid * 16 + i * 8) * 64);                       \
        }                                                                      \
    }

#define COMPUTE_TILE(KS, VS, T)                                                \
    {                                                                          \
        float bv[4][4];                                                        \
        _Pragma("unroll") for (int kt = 0; kt < 4; kt++)                       \
            _Pragma("unroll") for (int r = 0; r < 4; r++)                      \
                bv[kt][r] = bb[(size_t)(qw + 4 * g + r) * NSEQ + (T) * 64 + 16 * kt + li]; \
        f32x4 sacc[4];                                                         \
        _Pragma("unroll") for (int kt = 0; kt < 4; kt++)                       \
            sacc[kt] = f32x4{0.f, 0.f, 0.f, 0.f};                              \
        _Pragma("unroll") for (int kt = 0; kt < 4; kt++)                       \
            _Pragma("unroll") for (int dd = 0; dd < 2; dd++) {                 \
                bf16x8 kf = *reinterpret_cast<const bf16x8*>(                  \
                    (KS) + (16 * kt + li) * 64 + (((4 * dd + g) ^ (li & 7)) * 8)); \
                sacc[kt] = __builtin_amdgcn_mfma_f32_16x16x32_bf16(qf[dd], kf, sacc[kt], 0, 0, 0); \
            }                                                                  \
        _Pragma("unroll") for (int kt = 0; kt < 4; kt++)                       \
            _Pragma("unroll") for (int r = 0; r < 4; r++) {                    \
                float pv = __expf(sacc[kt][r] + bv[kt][r]);                    \
                lpart[r] += pv;                                                \
                Ps[wid][4 * g + r][16 * kt + li] = f2bf(pv);                   \
            }                                                                  \
        _Pragma("unroll") for (int kk = 0; kk < 2; kk++) {                     \
            bf16x8 pf = *reinterpret_cast<const bf16x8*>(&Ps[wid][li][32 * kk + 8 * g]); \
            _Pragma("unroll") for (int dt = 0; dt < 4; dt++) {                 \
                bf16x8 vf = *reinterpret_cast<const bf16x8*>(                  \
                    (VS) + (16 * dt + li) * 64 + (((4 * kk + g) ^ (li & 7)) * 8)); \
                oacc[dt] = __builtin_amdgcn_mfma_f32_16x16x32_bf16(pf, vf, oacc[dt], 0, 0, 0); \
            }                                                                  \
        }                                                                      \
    }

    bf16x8 qf[2];
    #pragma unroll
    for (int dd = 0; dd < 2; dd++)
        qf[dd] = *reinterpret_cast<const bf16x8*>(&qb[(size_t)(qw + li) * HDIM + 32 * dd + 8 * g]);

    f32x4 oacc[4];
    #pragma unroll
    for (int dt = 0; dt < 4; dt++) oacc[dt] = f32x4{0.f, 0.f, 0.f, 0.f};
    float lpart[4] = {0.f, 0.f, 0.f, 0.f};

    STAGE_KV(0, Kl[0], Vl[0]);
    __syncthreads();

    for (int j = 0; j < 8; ++j) {
        const int tA = 2 * j;
        STAGE_KV(tA + 1, Kl[1], Vl[1]);
        COMPUTE_TILE(Kl[0], Vl[0], tA);
        __syncthreads();

        if (j < 7) STAGE_KV(tA + 2, Kl[0], Vl[0]);
        COMPUTE_TILE(Kl[1], Vl[1], tA + 1);
        __syncthreads();
    }

    float linv[4];
    #pragma unroll
    for (int r = 0; r < 4; r++) {
        float s = lpart[r];
        s += __shfl_xor(s, 1);
        s += __shfl_xor(s, 2);
        s += __shfl_xor(s, 4);
        s += __shfl_xor(s, 8);
        linv[r] = 1.f / s;
    }
    #pragma unroll
    for (int dt = 0; dt < 4; dt++)
        #pragma unroll
        for (int r = 0; r < 4; r++) {
            float o = oacc[dt][r] * linv[r];
            int sq = qw + 4 * g + r;
            ybuf[((size_t)b_ * NSEQ + sq) * CDIM + h_ * HDIM + 16 * dt + li] = f2bf(o);
        }
#undef STAGE_KV
#undef COMPUTE_TILE
}

// ---------------------------------------------------------------------------
// Proj GEMM: r19 version (64x128 tile, BK=32, async dbuf, 2-way swizzle).
// ---------------------------------------------------------------------------
__global__ __launch_bounds__(256) void proj_gemm(
    const unsigned short* __restrict__ yb,   // [4096][768]
    const unsigned short* __restrict__ pwt,  // [768][768] (n,k)
    const float* __restrict__ bias, float* __restrict__ out)
{
    __shared__ unsigned short A0[64 * 32], A1[64 * 32];
    __shared__ unsigned short B0[128 * 32], B1[128 * 32];
    const int tid  = threadIdx.x;
    const int lane = tid & 63;
    const int wid  = tid >> 6;
    const int wr = (wid >> 1) * 32, wc = (wid & 1) * 64;
    const int g = lane >> 4, li = lane & 15;
    const int m0 = blockIdx.y * 64;
    const int n0 = blockIdx.x * 128;
    const int srow = lane >> 2;
    const int scol = ((lane & 3) ^ ((lane >> 3) & 3)) * 8;
    const int rsl  = (g ^ ((li >> 1) & 3)) * 8;

#define PSTAGE(K0, AD, BD)                                                     \
    {                                                                          \
        GLOAD_LDS16(&yb[(size_t)(m0 + wid * 16 + srow) * CDIM + (K0) + scol],  \
                    (AD) + wid * 16 * 32);                                     \
        _Pragma("unroll") for (int c = 0; c < 2; c++)                          \
            GLOAD_LDS16(&pwt[(size_t)(n0 + wid * 32 + c * 16 + srow) * CDIM + (K0) + scol], \
                        (BD) + (wid * 32 + c * 16) * 32);                      \
    }

#define PCOMPUTE(AS, BS)                                                       \
    {                                                                          \
        bf16x8 a[2], b[4];                                                     \
        _Pragma("unroll") for (int mt = 0; mt < 2; mt++)                       \
            a[mt] = *reinterpret_cast<const bf16x8*>(                          \
                (AS) + (wr + 16 * mt + li) * 32 + rsl);                        \
        _Pragma("unroll") for (int nt = 0; nt < 4; nt++)                       \
            b[nt] = *reinterpret_cast<const bf16x8*>(                          \
                (BS) + (wc + 16 * nt + li) * 32 + rsl);                        \
        _Pragma("unroll") for (int mt = 0; mt < 2; mt++)                       \
            _Pragma("unroll") for (int nt = 0; nt < 4; nt++)                   \
                acc[mt][nt] = __builtin_amdgcn_mfma_f32_16x16x32_bf16(         \
                    a[mt], b[nt], acc[mt][nt], 0, 0, 0);                       \
    }

    f32x4 acc[2][4];
    #pragma unroll
    for (int i = 0; i < 2; i++)
        #pragma unroll
        for (int j = 0; j < 4; j++) acc[i][j] = f32x4{0.f, 0.f, 0.f, 0.f};

    PSTAGE(0, A0, B0);
    __syncthreads();

    for (int j = 0; j < 12; ++j) {
        const int k0 = j * 64;
        PSTAGE(k0 + 32, A1, B1);
        PCOMPUTE(A0, B0);
        __syncthreads();
        if (j < 11) PSTAGE(k0 + 64, A0, B0);
        PCOMPUTE(A1, B1);
        __syncthreads();
    }

    #pragma unroll
    for (int mt = 0; mt < 2; mt++)
        #pragma unroll
        for (int nt = 0; nt < 4; nt++) {
            int col = n0 + wc + 16 * nt + li;
            float bv = bias[col];
            #pragma unroll
            for (int r = 0; r < 4; r++) {
                int m = m0 + wr + 16 * mt + 4 * g + r;
                out[(size_t)m * CDIM + col] = acc[mt][nt][r] + bv;
            }
        }
#undef PSTAGE
#undef PCOMPUTE
}

extern "C" void kernel_launch(void* const* d_in, const int* in_sizes, int n_in,
                              void* d_out, int out_size, void* d_ws, size_t ws_size,
                              hipStream_t stream) {
    const float* x         = (const float*)d_in[0];
    const float* attn_bias = (const float*)d_in[1];
    const float* qkv_w     = (const float*)d_in[2];
    const float* qkv_b     = (const float*)d_in[3];
    const float* proj_w    = (const float*)d_in[4];
    const float* proj_b    = (const float*)d_in[5];
    float* out = (float*)d_out;

    const size_t per = (size_t)BATCH * NHEAD * NSEQ * HDIM;  // 3,145,728
    unsigned short* qbuf  = (unsigned short*)d_ws;
    unsigned short* kbuf  = qbuf + per;
    unsigned short* vtbuf = kbuf + per;
    unsigned short* xb    = vtbuf + per;
    unsigned short* qwt   = xb + per;                    // [2304][768]
    unsigned short* pwt   = qwt + (size_t)QKVN * CDIM;   // [768][768]
    unsigned short* ybuf  = xb;  // x dead after qkv_gemm

    prep_kernel<<<NB_X + NB_QW + NB_PW, 256, 0, stream>>>(
        x, xb, qkv_w, qwt, proj_w, pwt);

    qkv_gemm<<<dim3(QKVN / 128, MTOT / 64), 256, 0, stream>>>(
        xb, qwt, qkv_b, qbuf, kbuf, vtbuf);
    attn_kernel<<<dim3(NSEQ / 64, BATCH * NHEAD), 256, 0, stream>>>(
        qbuf, kbuf, vtbuf, attn_bias, ybuf);
    proj_gemm<<<dim3(CDIM / 128, MTOT / 64), 256, 0, stream>>>(
        ybuf, pwt, proj_b, out);
}

// Round 21
// 97.189 us; speedup vs baseline: 1.1003x; 1.0188x over previous
//
#include <hip/hip_runtime.h>
#include <hip/hip_bf16.h>

// Problem constants
constexpr int BATCH = 4;
constexpr int NSEQ  = 1024;
constexpr int CDIM  = 768;
constexpr int NHEAD = 12;
constexpr int HDIM  = 64;
constexpr int MTOT  = BATCH * NSEQ;   // 4096
constexpr int QKVN  = 3 * CDIM;       // 2304

typedef __bf16 bf16x8 __attribute__((ext_vector_type(8)));
typedef float  f32x4  __attribute__((ext_vector_type(4)));

__device__ __forceinline__ unsigned short f2bf(float f) {
    unsigned u = __builtin_bit_cast(unsigned, f);
    unsigned r = u + 0x7FFFu + ((u >> 16) & 1u);   // RNE
    return (unsigned short)(r >> 16);
}

#define GLOAD_LDS16(gp, lp)                                                    \
    __builtin_amdgcn_global_load_lds(                                          \
        (const __attribute__((address_space(1))) void*)(gp),                   \
        (__attribute__((address_space(3))) void*)(lp), 16, 0, 0)

// ---------------------------------------------------------------------------
// Fused prologue: ONE kernel does all three conversions (r18 win).
// ---------------------------------------------------------------------------
constexpr int NB_X  = MTOT * CDIM / 4 / 256;       // 3072
constexpr int NB_QW = (QKVN / 32) * (CDIM / 32);   // 1728
constexpr int NB_PW = (CDIM / 32) * (CDIM / 32);   // 576

__device__ __forceinline__ void tcvt_tile(
    const float* __restrict__ in, unsigned short* __restrict__ out,
    int R, int C, int c0, int r0, int tid)
{
    __shared__ unsigned short t[32][33];
    const int tc = tid & 31, tr = tid >> 5;  // tr 0..7
    #pragma unroll
    for (int i = 0; i < 4; i++)
        t[tc][tr + 8 * i] = f2bf(in[(size_t)(r0 + tr + 8 * i) * C + c0 + tc]);
    __syncthreads();
    #pragma unroll
    for (int i = 0; i < 4; i++)
        out[(size_t)(c0 + tr + 8 * i) * R + r0 + tc] = t[tr + 8 * i][tc];
}

__global__ __launch_bounds__(256) void prep_kernel(
    const float* __restrict__ x,      unsigned short* __restrict__ xb,
    const float* __restrict__ qkv_w,  unsigned short* __restrict__ qwt,
    const float* __restrict__ proj_w, unsigned short* __restrict__ pwt)
{
    const int bid = blockIdx.x;
    const int tid = threadIdx.x;
    if (bid < NB_X) {
        int i = bid * 256 + tid;
        float4 a = reinterpret_cast<const float4*>(x)[i];
        ushort4 h;
        h.x = f2bf(a.x); h.y = f2bf(a.y); h.z = f2bf(a.z); h.w = f2bf(a.w);
        reinterpret_cast<ushort4*>(xb)[i] = h;
    } else if (bid < NB_X + NB_QW) {
        int t = bid - NB_X;
        tcvt_tile(qkv_w, qwt, CDIM, QKVN, (t % (QKVN / 32)) * 32,
                  (t / (QKVN / 32)) * 32, tid);
    } else {
        int t = bid - NB_X - NB_QW;
        tcvt_tile(proj_w, pwt, CDIM, CDIM, (t % (CDIM / 32)) * 32,
                  (t / (CDIM / 32)) * 32, tid);
    }
}

// ---------------------------------------------------------------------------
// QKV GEMM: r20 version (64x128, BK=32, swizzled LDS, 3-deep counted-vmcnt
// pipeline). Kept — r20 was the best total.
// ---------------------------------------------------------------------------
__global__ __launch_bounds__(256) void qkv_gemm(
    const unsigned short* __restrict__ xb,   // [4096][768]
    const unsigned short* __restrict__ wt,   // [2304][768]
    const float* __restrict__ bias,
    unsigned short* __restrict__ qbuf, unsigned short* __restrict__ kbuf,
    unsigned short* __restrict__ vtbuf)
{
    __shared__ unsigned short A0[64 * 32], A1[64 * 32], A2[64 * 32];
    __shared__ unsigned short B0[128 * 32], B1[128 * 32], B2[128 * 32];
    const int tid  = threadIdx.x;
    const int lane = tid & 63;
    const int wid  = tid >> 6;
    const int wr = (wid >> 1) * 32, wc = (wid & 1) * 64;
    const int g = lane >> 4, li = lane & 15;
    const int m0 = blockIdx.y * 64;
    const int n0 = blockIdx.x * 128;
    const int srow = lane >> 2;                               // 0..15
    const int scol = ((lane & 3) ^ ((lane >> 3) & 3)) * 8;    // swizzled src col
    const int rsl  = (g ^ ((li >> 1) & 3)) * 8;               // swizzled read col

#define QSTAGE(K0, AD, BD)                                                     \
    {                                                                          \
        GLOAD_LDS16(&xb[(size_t)(m0 + wid * 16 + srow) * CDIM + (K0) + scol],  \
                    (AD) + wid * 16 * 32);                                     \
        _Pragma("unroll") for (int c = 0; c < 2; c++)                          \
            GLOAD_LDS16(&wt[(size_t)(n0 + wid * 32 + c * 16 + srow) * CDIM + (K0) + scol], \
                        (BD) + (wid * 32 + c * 16) * 32);                      \
    }

#define QCOMPUTE(AS, BS)                                                       \
    {                                                                          \
        bf16x8 a[2], b[4];                                                     \
        _Pragma("unroll") for (int mt = 0; mt < 2; mt++)                       \
            a[mt] = *reinterpret_cast<const bf16x8*>(                          \
                (AS) + (wr + 16 * mt + li) * 32 + rsl);                        \
        _Pragma("unroll") for (int nt = 0; nt < 4; nt++)                       \
            b[nt] = *reinterpret_cast<const bf16x8*>(                          \
                (BS) + (wc + 16 * nt + li) * 32 + rsl);                        \
        _Pragma("unroll") for (int mt = 0; mt < 2; mt++)                       \
            _Pragma("unroll") for (int nt = 0; nt < 4; nt++)                   \
                acc[mt][nt] = __builtin_amdgcn_mfma_f32_16x16x32_bf16(         \
                    a[mt], b[nt], acc[mt][nt], 0, 0, 0);                       \
    }

#define WAITBAR3()                                                             \
    {                                                                          \
        asm volatile("s_waitcnt vmcnt(3)" ::: "memory");                       \
        __builtin_amdgcn_sched_barrier(0);                                     \
        __builtin_amdgcn_s_barrier();                                          \
        __builtin_amdgcn_sched_barrier(0);                                     \
    }
#define WAITBAR0()                                                             \
    {                                                                          \
        asm volatile("s_waitcnt vmcnt(0)" ::: "memory");                       \
        __builtin_amdgcn_sched_barrier(0);                                     \
        __builtin_amdgcn_s_barrier();                                          \
        __builtin_amdgcn_sched_barrier(0);                                     \
    }

    f32x4 acc[2][4];
    #pragma unroll
    for (int i = 0; i < 2; i++)
        #pragma unroll
        for (int j = 0; j < 4; j++) acc[i][j] = f32x4{0.f, 0.f, 0.f, 0.f};

    QSTAGE(0, A0, B0);
    QSTAGE(32, A1, B1);
    WAITBAR3();

    for (int j = 0; j < 8; ++j) {
        const int k0 = j * 96;
        QSTAGE(k0 + 64, A2, B2);
        QCOMPUTE(A0, B0);
        WAITBAR3();
        if (j < 7) {
            QSTAGE(k0 + 96, A0, B0);
            QCOMPUTE(A1, B1);
            WAITBAR3();
            QSTAGE(k0 + 128, A1, B1);
            QCOMPUTE(A2, B2);
            WAITBAR3();
        } else {
            QCOMPUTE(A1, B1);
            WAITBAR0();
            QCOMPUTE(A2, B2);
        }
    }

    #pragma unroll
    for (int mt = 0; mt < 2; mt++) {
        #pragma unroll
        for (int nt = 0; nt < 4; nt++) {
            int col  = n0 + wc + 16 * nt + li;
            int tsel = col / CDIM;
            int rem  = col - tsel * CDIM;
            int h_ = rem >> 6, d = rem & 63;
            float bv = bias[col];
            float sc = (tsel == 0) ? 0.125f : 1.0f;
            #pragma unroll
            for (int r = 0; r < 4; r++) {
                int m  = m0 + wr + 16 * mt + 4 * g + r;
                int b_ = m >> 10, s = m & 1023;
                unsigned short hv = f2bf((acc[mt][nt][r] + bv) * sc);
                if (tsel == 0)
                    qbuf[(((size_t)b_ * NHEAD + h_) * NSEQ + s) * HDIM + d] = hv;
                else if (tsel == 1)
                    kbuf[(((size_t)b_ * NHEAD + h_) * NSEQ + s) * HDIM + d] = hv;
                else
                    vtbuf[(((size_t)b_ * NHEAD + h_) * HDIM + d) * NSEQ + s] = hv;
            }
        }
    }
#undef QSTAGE
#undef QCOMPUTE
#undef WAITBAR3
#undef WAITBAR0
}

// ---------------------------------------------------------------------------
// Flash-style attention — r10 body EXACT, flat grid with bias/KV-sharing
// XCD-chunked remap (bijective: 768 = 8 x 96). s = b + 4*(qtile + 16*h):
// 4 batches sharing identical bias rows are consecutive (same XCD -> bias
// L2-hit for 3 of 4 readers); 64 blocks of one h (4b x 16qt) chunk onto one
// XCD (K/V L2-resident). Converts the in-phase bias loads from L3 (~500cy)
// to L2 (~200cy) latency — the exposed chain after QK^T.
// ---------------------------------------------------------------------------
__global__ __launch_bounds__(256, 3) void attn_kernel(
    const unsigned short* __restrict__ qbuf,
    const unsigned short* __restrict__ kbuf,
    const unsigned short* __restrict__ vtbuf,
    const float* __restrict__ bias,     // [H,N,N]
    unsigned short* __restrict__ ybuf)  // [B,N,C] bf16
{
    __shared__ unsigned short Kl[2][64 * 64];  // [k][d] linear, source-swizzled
    __shared__ unsigned short Vl[2][64 * 64];  // V^T [d][k] linear, swizzled
    __shared__ unsigned short Ps[4][16][72];   // per-wave P: [q][k]

    const int tid  = threadIdx.x;
    const int lane = tid & 63;
    const int wid  = tid >> 6;
    const int g = lane >> 4, li = lane & 15;
    const int srow8 = lane >> 3;               // 0..7
    const int scs   = (lane & 7) ^ srow8;      // swizzled source slot (16B units)

    // XCD-chunked decode: lin 0..767 -> s bijective; s = b + 4*(qtile+16*h)
    const int lin = blockIdx.x;
    const int s   = (lin & 7) * 96 + (lin >> 3);
    const int b_    = s & 3;
    const int qtile = (s >> 2) & 15;
    const int h_    = s >> 6;                  // 0..11
    const int bh    = b_ * NHEAD + h_;
    const int qw = qtile * 64 + wid * 16;

    const unsigned short* qb = qbuf + (size_t)bh * NSEQ * HDIM;
    const unsigned short* kb = kbuf + (size_t)bh * NSEQ * HDIM;
    const unsigned short* vb = vtbuf + (size_t)bh * HDIM * NSEQ;
    const float* bb = bias + (size_t)h_ * NSEQ * NSEQ;

#define STAGE_KV(T, KL, VL)                                                    \
    {                                                                          \
        _Pragma("unroll") for (int i = 0; i < 2; i++) {                        \
            GLOAD_LDS16(kb + (size_t)((T) * 64 + wid * 16 + i * 8 + srow8) * HDIM + scs * 8, \
                        (KL) + (wid * 16 + i * 8) * 64);                       \
            GLOAD_LDS16(vb + (size_t)(wid * 16 + i * 8 + srow8) * NSEQ + (T) * 64 + scs * 8, \
                        (VL) + (wid * 16 + i * 8) * 64);                       \
        }                                                                      \
    }

#define COMPUTE_TILE(KS, VS, T)                                                \
    {                                                                          \
        float bv[4][4];                                                        \
        _Pragma("unroll") for (int kt = 0; kt < 4; kt++)                       \
            _Pragma("unroll") for (int r = 0; r < 4; r++)                      \
                bv[kt][r] = bb[(size_t)(qw + 4 * g + r) * NSEQ + (T) * 64 + 16 * kt + li]; \
        f32x4 sacc[4];                                                         \
        _Pragma("unroll") for (int kt = 0; kt < 4; kt++)                       \
            sacc[kt] = f32x4{0.f, 0.f, 0.f, 0.f};                              \
        _Pragma("unroll") for (int kt = 0; kt < 4; kt++)                       \
            _Pragma("unroll") for (int dd = 0; dd < 2; dd++) {                 \
                bf16x8 kf = *reinterpret_cast<const bf16x8*>(                  \
                    (KS) + (16 * kt + li) * 64 + (((4 * dd + g) ^ (li & 7)) * 8)); \
                sacc[kt] = __builtin_amdgcn_mfma_f32_16x16x32_bf16(qf[dd], kf, sacc[kt], 0, 0, 0); \
            }                                                                  \
        _Pragma("unroll") for (int kt = 0; kt < 4; kt++)                       \
            _Pragma("unroll") for (int r = 0; r < 4; r++) {                    \
                float pv = __expf(sacc[kt][r] + bv[kt][r]);                    \
                lpart[r] += pv;                                                \
                Ps[wid][4 * g + r][16 * kt + li] = f2bf(pv);                   \
            }                                                                  \
        _Pragma("unroll") for (int kk = 0; kk < 2; kk++) {                     \
            bf16x8 pf = *reinterpret_cast<const bf16x8*>(&Ps[wid][li][32 * kk + 8 * g]); \
            _Pragma("unroll") for (int dt = 0; dt < 4; dt++) {                 \
                bf16x8 vf = *reinterpret_cast<const bf16x8*>(                  \
                    (VS) + (16 * dt + li) * 64 + (((4 * kk + g) ^ (li & 7)) * 8)); \
                oacc[dt] = __builtin_amdgcn_mfma_f32_16x16x32_bf16(pf, vf, oacc[dt], 0, 0, 0); \
            }                                                                  \
        }                                                                      \
    }

    bf16x8 qf[2];
    #pragma unroll
    for (int dd = 0; dd < 2; dd++)
        qf[dd] = *reinterpret_cast<const bf16x8*>(&qb[(size_t)(qw + li) * HDIM + 32 * dd + 8 * g]);

    f32x4 oacc[4];
    #pragma unroll
    for (int dt = 0; dt < 4; dt++) oacc[dt] = f32x4{0.f, 0.f, 0.f, 0.f};
    float lpart[4] = {0.f, 0.f, 0.f, 0.f};

    STAGE_KV(0, Kl[0], Vl[0]);
    __syncthreads();

    for (int j = 0; j < 8; ++j) {
        const int tA = 2 * j;
        STAGE_KV(tA + 1, Kl[1], Vl[1]);
        COMPUTE_TILE(Kl[0], Vl[0], tA);
        __syncthreads();

        if (j < 7) STAGE_KV(tA + 2, Kl[0], Vl[0]);
        COMPUTE_TILE(Kl[1], Vl[1], tA + 1);
        __syncthreads();
    }

    float linv[4];
    #pragma unroll
    for (int r = 0; r < 4; r++) {
        float s2 = lpart[r];
        s2 += __shfl_xor(s2, 1);
        s2 += __shfl_xor(s2, 2);
        s2 += __shfl_xor(s2, 4);
        s2 += __shfl_xor(s2, 8);
        linv[r] = 1.f / s2;
    }
    #pragma unroll
    for (int dt = 0; dt < 4; dt++)
        #pragma unroll
        for (int r = 0; r < 4; r++) {
            float o = oacc[dt][r] * linv[r];
            int sq = qw + 4 * g + r;
            ybuf[((size_t)b_ * NSEQ + sq) * CDIM + h_ * HDIM + 16 * dt + li] = f2bf(o);
        }
#undef STAGE_KV
#undef COMPUTE_TILE
}

// ---------------------------------------------------------------------------
// Proj GEMM: r19 version (64x128 tile, BK=32, async dbuf, 2-way swizzle).
// ---------------------------------------------------------------------------
__global__ __launch_bounds__(256) void proj_gemm(
    const unsigned short* __restrict__ yb,   // [4096][768]
    const unsigned short* __restrict__ pwt,  // [768][768] (n,k)
    const float* __restrict__ bias, float* __restrict__ out)
{
    __shared__ unsigned short A0[64 * 32], A1[64 * 32];
    __shared__ unsigned short B0[128 * 32], B1[128 * 32];
    const int tid  = threadIdx.x;
    const int lane = tid & 63;
    const int wid  = tid >> 6;
    const int wr = (wid >> 1) * 32, wc = (wid & 1) * 64;
    const int g = lane >> 4, li = lane & 15;
    const int m0 = blockIdx.y * 64;
    const int n0 = blockIdx.x * 128;
    const int srow = lane >> 2;
    const int scol = ((lane & 3) ^ ((lane >> 3) & 3)) * 8;
    const int rsl  = (g ^ ((li >> 1) & 3)) * 8;

#define PSTAGE(K0, AD, BD)                                                     \
    {                                                                          \
        GLOAD_LDS16(&yb[(size_t)(m0 + wid * 16 + srow) * CDIM + (K0) + scol],  \
                    (AD) + wid * 16 * 32);                                     \
        _Pragma("unroll") for (int c = 0; c < 2; c++)                          \
            GLOAD_LDS16(&pwt[(size_t)(n0 + wid * 32 + c * 16 + srow) * CDIM + (K0) + scol], \
                        (BD) + (wid * 32 + c * 16) * 32);                      \
    }

#define PCOMPUTE(AS, BS)                                                       \
    {                                                                          \
        bf16x8 a[2], b[4];                                                     \
        _Pragma("unroll") for (int mt = 0; mt < 2; mt++)                       \
            a[mt] = *reinterpret_cast<const bf16x8*>(                          \
                (AS) + (wr + 16 * mt + li) * 32 + rsl);                        \
        _Pragma("unroll") for (int nt = 0; nt < 4; nt++)                       \
            b[nt] = *reinterpret_cast<const bf16x8*>(                          \
                (BS) + (wc + 16 * nt + li) * 32 + rsl);                        \
        _Pragma("unroll") for (int mt = 0; mt < 2; mt++)                       \
            _Pragma("unroll") for (int nt = 0; nt < 4; nt++)                   \
                acc[mt][nt] = __builtin_amdgcn_mfma_f32_16x16x32_bf16(         \
                    a[mt], b[nt], acc[mt][nt], 0, 0, 0);                       \
    }

    f32x4 acc[2][4];
    #pragma unroll
    for (int i = 0; i < 2; i++)
        #pragma unroll
        for (int j = 0; j < 4; j++) acc[i][j] = f32x4{0.f, 0.f, 0.f, 0.f};

    PSTAGE(0, A0, B0);
    __syncthreads();

    for (int j = 0; j < 12; ++j) {
        const int k0 = j * 64;
        PSTAGE(k0 + 32, A1, B1);
        PCOMPUTE(A0, B0);
        __syncthreads();
        if (j < 11) PSTAGE(k0 + 64, A0, B0);
        PCOMPUTE(A1, B1);
        __syncthreads();
    }

    #pragma unroll
    for (int mt = 0; mt < 2; mt++)
        #pragma unroll
        for (int nt = 0; nt < 4; nt++) {
            int col = n0 + wc + 16 * nt + li;
            float bv = bias[col];
            #pragma unroll
            for (int r = 0; r < 4; r++) {
                int m = m0 + wr + 16 * mt + 4 * g + r;
                out[(size_t)m * CDIM + col] = acc[mt][nt][r] + bv;
            }
        }
#undef PSTAGE
#undef PCOMPUTE
}

extern "C" void kernel_launch(void* const* d_in, const int* in_sizes, int n_in,
                              void* d_out, int out_size, void* d_ws, size_t ws_size,
                              hipStream_t stream) {
    const float* x         = (const float*)d_in[0];
    const float* attn_bias = (const float*)d_in[1];
    const float* qkv_w     = (const float*)d_in[2];
    const float* qkv_b     = (const float*)d_in[3];
    const float* proj_w    = (const float*)d_in[4];
    const float* proj_b    = (const float*)d_in[5];
    float* out = (float*)d_out;

    const size_t per = (size_t)BATCH * NHEAD * NSEQ * HDIM;  // 3,145,728
    unsigned short* qbuf  = (unsigned short*)d_ws;
    unsigned short* kbuf  = qbuf + per;
    unsigned short* vtbuf = kbuf + per;
    unsigned short* xb    = vtbuf + per;
    unsigned short* qwt   = xb + per;                    // [2304][768]
    unsigned short* pwt   = qwt + (size_t)QKVN * CDIM;   // [768][768]
    unsigned short* ybuf  = xb;  // x dead after qkv_gemm

    prep_kernel<<<NB_X + NB_QW + NB_PW, 256, 0, stream>>>(
        x, xb, qkv_w, qwt, proj_w, pwt);

    qkv_gemm<<<dim3(QKVN / 128, MTOT / 64), 256, 0, stream>>>(
        xb, qwt, qkv_b, qbuf, kbuf, vtbuf);
    attn_kernel<<<768, 256, 0, stream>>>(
        qbuf, kbuf, vtbuf, attn_bias, ybuf);
    proj_gemm<<<dim3(CDIM / 128, MTOT / 64), 256, 0, stream>>>(
        ybuf, pwt, proj_b, out);
}

// Round 22
// 94.183 us; speedup vs baseline: 1.1355x; 1.0319x over previous
//
#include <hip/hip_runtime.h>
#include <hip/hip_bf16.h>

// Problem constants
constexpr int BATCH = 4;
constexpr int NSEQ  = 1024;
constexpr int CDIM  = 768;
constexpr int NHEAD = 12;
constexpr int HDIM  = 64;
constexpr int MTOT  = BATCH * NSEQ;   // 4096
constexpr int QKVN  = 3 * CDIM;       // 2304

typedef __bf16 bf16x8 __attribute__((ext_vector_type(8)));
typedef float  f32x4  __attribute__((ext_vector_type(4)));

__device__ __forceinline__ unsigned short f2bf(float f) {
    unsigned u = __builtin_bit_cast(unsigned, f);
    unsigned r = u + 0x7FFFu + ((u >> 16) & 1u);   // RNE
    return (unsigned short)(r >> 16);
}

#define GLOAD_LDS16(gp, lp)                                                    \
    __builtin_amdgcn_global_load_lds(                                          \
        (const __attribute__((address_space(1))) void*)(gp),                   \
        (__attribute__((address_space(3))) void*)(lp), 16, 0, 0)

// ---------------------------------------------------------------------------
// Fused prologue: ONE kernel does all three conversions (r18 win).
// ---------------------------------------------------------------------------
constexpr int NB_X  = MTOT * CDIM / 4 / 256;       // 3072
constexpr int NB_QW = (QKVN / 32) * (CDIM / 32);   // 1728
constexpr int NB_PW = (CDIM / 32) * (CDIM / 32);   // 576

__device__ __forceinline__ void tcvt_tile(
    const float* __restrict__ in, unsigned short* __restrict__ out,
    int R, int C, int c0, int r0, int tid)
{
    __shared__ unsigned short t[32][33];
    const int tc = tid & 31, tr = tid >> 5;  // tr 0..7
    #pragma unroll
    for (int i = 0; i < 4; i++)
        t[tc][tr + 8 * i] = f2bf(in[(size_t)(r0 + tr + 8 * i) * C + c0 + tc]);
    __syncthreads();
    #pragma unroll
    for (int i = 0; i < 4; i++)
        out[(size_t)(c0 + tr + 8 * i) * R + r0 + tc] = t[tr + 8 * i][tc];
}

__global__ __launch_bounds__(256) void prep_kernel(
    const float* __restrict__ x,      unsigned short* __restrict__ xb,
    const float* __restrict__ qkv_w,  unsigned short* __restrict__ qwt,
    const float* __restrict__ proj_w, unsigned short* __restrict__ pwt)
{
    const int bid = blockIdx.x;
    const int tid = threadIdx.x;
    if (bid < NB_X) {
        int i = bid * 256 + tid;
        float4 a = reinterpret_cast<const float4*>(x)[i];
        ushort4 h;
        h.x = f2bf(a.x); h.y = f2bf(a.y); h.z = f2bf(a.z); h.w = f2bf(a.w);
        reinterpret_cast<ushort4*>(xb)[i] = h;
    } else if (bid < NB_X + NB_QW) {
        int t = bid - NB_X;
        tcvt_tile(qkv_w, qwt, CDIM, QKVN, (t % (QKVN / 32)) * 32,
                  (t / (QKVN / 32)) * 32, tid);
    } else {
        int t = bid - NB_X - NB_QW;
        tcvt_tile(proj_w, pwt, CDIM, CDIM, (t % (CDIM / 32)) * 32,
                  (t / (CDIM / 32)) * 32, tid);
    }
}

// ---------------------------------------------------------------------------
// QKV GEMM: r20 body (64x128, BK=32, swizzled LDS, 3-deep counted-vmcnt
// pipeline) + XCD-chunked flat grid (1152 = 8 x 144, bijective):
// s = (lin&7)*144 + lin>>3; n = s%18, m = s/18 -> each XCD computes 8
// m-panels x ALL 18 n-panels: wt (3.5MB) fully L2-resident per XCD, xb
// panels L2-reused 18x. Stage latency HBM(~900cy) -> L2(~200cy), which the
// 3-deep pipeline's ~2-phase cover can fully hide.
// ---------------------------------------------------------------------------
__global__ __launch_bounds__(256) void qkv_gemm(
    const unsigned short* __restrict__ xb,   // [4096][768]
    const unsigned short* __restrict__ wt,   // [2304][768]
    const float* __restrict__ bias,
    unsigned short* __restrict__ qbuf, unsigned short* __restrict__ kbuf,
    unsigned short* __restrict__ vtbuf)
{
    __shared__ unsigned short A0[64 * 32], A1[64 * 32], A2[64 * 32];
    __shared__ unsigned short B0[128 * 32], B1[128 * 32], B2[128 * 32];
    const int tid  = threadIdx.x;
    const int lane = tid & 63;
    const int wid  = tid >> 6;
    const int wr = (wid >> 1) * 32, wc = (wid & 1) * 64;
    const int g = lane >> 4, li = lane & 15;

    // XCD-chunked decode (1152 % 8 == 0 -> bijective)
    const int lin = blockIdx.x;
    const int sdec = (lin & 7) * 144 + (lin >> 3);
    const int n0 = (sdec % 18) * 128;
    const int m0 = (sdec / 18) * 64;

    const int srow = lane >> 2;                               // 0..15
    const int scol = ((lane & 3) ^ ((lane >> 3) & 3)) * 8;    // swizzled src col
    const int rsl  = (g ^ ((li >> 1) & 3)) * 8;               // swizzled read col

#define QSTAGE(K0, AD, BD)                                                     \
    {                                                                          \
        GLOAD_LDS16(&xb[(size_t)(m0 + wid * 16 + srow) * CDIM + (K0) + scol],  \
                    (AD) + wid * 16 * 32);                                     \
        _Pragma("unroll") for (int c = 0; c < 2; c++)                          \
            GLOAD_LDS16(&wt[(size_t)(n0 + wid * 32 + c * 16 + srow) * CDIM + (K0) + scol], \
                        (BD) + (wid * 32 + c * 16) * 32);                      \
    }

#define QCOMPUTE(AS, BS)                                                       \
    {                                                                          \
        bf16x8 a[2], b[4];                                                     \
        _Pragma("unroll") for (int mt = 0; mt < 2; mt++)                       \
            a[mt] = *reinterpret_cast<const bf16x8*>(                          \
                (AS) + (wr + 16 * mt + li) * 32 + rsl);                        \
        _Pragma("unroll") for (int nt = 0; nt < 4; nt++)                       \
            b[nt] = *reinterpret_cast<const bf16x8*>(                          \
                (BS) + (wc + 16 * nt + li) * 32 + rsl);                        \
        _Pragma("unroll") for (int mt = 0; mt < 2; mt++)                       \
            _Pragma("unroll") for (int nt = 0; nt < 4; nt++)                   \
                acc[mt][nt] = __builtin_amdgcn_mfma_f32_16x16x32_bf16(         \
                    a[mt], b[nt], acc[mt][nt], 0, 0, 0);                       \
    }

#define WAITBAR3()                                                             \
    {                                                                          \
        asm volatile("s_waitcnt vmcnt(3)" ::: "memory");                       \
        __builtin_amdgcn_sched_barrier(0);                                     \
        __builtin_amdgcn_s_barrier();                                          \
        __builtin_amdgcn_sched_barrier(0);                                     \
    }
#define WAITBAR0()                                                             \
    {                                                                          \
        asm volatile("s_waitcnt vmcnt(0)" ::: "memory");                       \
        __builtin_amdgcn_sched_barrier(0);                                     \
        __builtin_amdgcn_s_barrier();                                          \
        __builtin_amdgcn_sched_barrier(0);                                     \
    }

    f32x4 acc[2][4];
    #pragma unroll
    for (int i = 0; i < 2; i++)
        #pragma unroll
        for (int j = 0; j < 4; j++) acc[i][j] = f32x4{0.f, 0.f, 0.f, 0.f};

    QSTAGE(0, A0, B0);
    QSTAGE(32, A1, B1);
    WAITBAR3();

    for (int j = 0; j < 8; ++j) {
        const int k0 = j * 96;
        QSTAGE(k0 + 64, A2, B2);
        QCOMPUTE(A0, B0);
        WAITBAR3();
        if (j < 7) {
            QSTAGE(k0 + 96, A0, B0);
            QCOMPUTE(A1, B1);
            WAITBAR3();
            QSTAGE(k0 + 128, A1, B1);
            QCOMPUTE(A2, B2);
            WAITBAR3();
        } else {
            QCOMPUTE(A1, B1);
            WAITBAR0();
            QCOMPUTE(A2, B2);
        }
    }

    #pragma unroll
    for (int mt = 0; mt < 2; mt++) {
        #pragma unroll
        for (int nt = 0; nt < 4; nt++) {
            int col  = n0 + wc + 16 * nt + li;
            int tsel = col / CDIM;
            int rem  = col - tsel * CDIM;
            int h_ = rem >> 6, d = rem & 63;
            float bv = bias[col];
            float sc = (tsel == 0) ? 0.125f : 1.0f;
            #pragma unroll
            for (int r = 0; r < 4; r++) {
                int m  = m0 + wr + 16 * mt + 4 * g + r;
                int b_ = m >> 10, s = m & 1023;
                unsigned short hv = f2bf((acc[mt][nt][r] + bv) * sc);
                if (tsel == 0)
                    qbuf[(((size_t)b_ * NHEAD + h_) * NSEQ + s) * HDIM + d] = hv;
                else if (tsel == 1)
                    kbuf[(((size_t)b_ * NHEAD + h_) * NSEQ + s) * HDIM + d] = hv;
                else
                    vtbuf[(((size_t)b_ * NHEAD + h_) * HDIM + d) * NSEQ + s] = hv;
            }
        }
    }
#undef QSTAGE
#undef QCOMPUTE
#undef WAITBAR3
#undef WAITBAR0
}

// ---------------------------------------------------------------------------
// Flash-style attention — r21 version (r10 body + bias/KV-sharing XCD remap).
// ---------------------------------------------------------------------------
__global__ __launch_bounds__(256, 3) void attn_kernel(
    const unsigned short* __restrict__ qbuf,
    const unsigned short* __restrict__ kbuf,
    const unsigned short* __restrict__ vtbuf,
    const float* __restrict__ bias,     // [H,N,N]
    unsigned short* __restrict__ ybuf)  // [B,N,C] bf16
{
    __shared__ unsigned short Kl[2][64 * 64];  // [k][d] linear, source-swizzled
    __shared__ unsigned short Vl[2][64 * 64];  // V^T [d][k] linear, swizzled
    __shared__ unsigned short Ps[4][16][72];   // per-wave P: [q][k]

    const int tid  = threadIdx.x;
    const int lane = tid & 63;
    const int wid  = tid >> 6;
    const int g = lane >> 4, li = lane & 15;
    const int srow8 = lane >> 3;               // 0..7
    const int scs   = (lane & 7) ^ srow8;      // swizzled source slot (16B units)

    // XCD-chunked decode: s = b + 4*(qtile+16*h), bijective (768 = 8 x 96)
    const int lin = blockIdx.x;
    const int s   = (lin & 7) * 96 + (lin >> 3);
    const int b_    = s & 3;
    const int qtile = (s >> 2) & 15;
    const int h_    = s >> 6;                  // 0..11
    const int bh    = b_ * NHEAD + h_;
    const int qw = qtile * 64 + wid * 16;

    const unsigned short* qb = qbuf + (size_t)bh * NSEQ * HDIM;
    const unsigned short* kb = kbuf + (size_t)bh * NSEQ * HDIM;
    const unsigned short* vb = vtbuf + (size_t)bh * HDIM * NSEQ;
    const float* bb = bias + (size_t)h_ * NSEQ * NSEQ;

#define STAGE_KV(T, KL, VL)                                                    \
    {                                                                          \
        _Pragma("unroll") for (int i = 0; i < 2; i++) {                        \
            GLOAD_LDS16(kb + (size_t)((T) * 64 + wid * 16 + i * 8 + srow8) * HDIM + scs * 8, \
                        (KL) + (wid * 16 + i * 8) * 64);                       \
            GLOAD_LDS16(vb + (size_t)(wid * 16 + i * 8 + srow8) * NSEQ + (T) * 64 + scs * 8, \
                        (VL) + (wid * 16 + i * 8) * 64);                       \
        }                                                                      \
    }

#define COMPUTE_TILE(KS, VS, T)                                                \
    {                                                                          \
        float bv[4][4];                                                        \
        _Pragma("unroll") for (int kt = 0; kt < 4; kt++)                       \
            _Pragma("unroll") for (int r = 0; r < 4; r++)                      \
                bv[kt][r] = bb[(size_t)(qw + 4 * g + r) * NSEQ + (T) * 64 + 16 * kt + li]; \
        f32x4 sacc[4];                                                         \
        _Pragma("unroll") for (int kt = 0; kt < 4; kt++)                       \
            sacc[kt] = f32x4{0.f, 0.f, 0.f, 0.f};                              \
        _Pragma("unroll") for (int kt = 0; kt < 4; kt++)                       \
            _Pragma("unroll") for (int dd = 0; dd < 2; dd++) {                 \
                bf16x8 kf = *reinterpret_cast<const bf16x8*>(                  \
                    (KS) + (16 * kt + li) * 64 + (((4 * dd + g) ^ (li & 7)) * 8)); \
                sacc[kt] = __builtin_amdgcn_mfma_f32_16x16x32_bf16(qf[dd], kf, sacc[kt], 0, 0, 0); \
            }                                                                  \
        _Pragma("unroll") for (int kt = 0; kt < 4; kt++)                       \
            _Pragma("unroll") for (int r = 0; r < 4; r++) {                    \
                float pv = __expf(sacc[kt][r] + bv[kt][r]);                    \
                lpart[r] += pv;                                                \
                Ps[wid][4 * g + r][16 * kt + li] = f2bf(pv);                   \
            }                                                                  \
        _Pragma("unroll") for (int kk = 0; kk < 2; kk++) {                     \
            bf16x8 pf = *reinterpret_cast<const bf16x8*>(&Ps[wid][li][32 * kk + 8 * g]); \
            _Pragma("unroll") for (int dt = 0; dt < 4; dt++) {                 \
                bf16x8 vf = *reinterpret_cast<const bf16x8*>(                  \
                    (VS) + (16 * dt + li) * 64 + (((4 * kk + g) ^ (li & 7)) * 8)); \
                oacc[dt] = __builtin_amdgcn_mfma_f32_16x16x32_bf16(pf, vf, oacc[dt], 0, 0, 0); \
            }                                                                  \
        }                                                                      \
    }

    bf16x8 qf[2];
    #pragma unroll
    for (int dd = 0; dd < 2; dd++)
        qf[dd] = *reinterpret_cast<const bf16x8*>(&qb[(size_t)(qw + li) * HDIM + 32 * dd + 8 * g]);

    f32x4 oacc[4];
    #pragma unroll
    for (int dt = 0; dt < 4; dt++) oacc[dt] = f32x4{0.f, 0.f, 0.f, 0.f};
    float lpart[4] = {0.f, 0.f, 0.f, 0.f};

    STAGE_KV(0, Kl[0], Vl[0]);
    __syncthreads();

    for (int j = 0; j < 8; ++j) {
        const int tA = 2 * j;
        STAGE_KV(tA + 1, Kl[1], Vl[1]);
        COMPUTE_TILE(Kl[0], Vl[0], tA);
        __syncthreads();

        if (j < 7) STAGE_KV(tA + 2, Kl[0], Vl[0]);
        COMPUTE_TILE(Kl[1], Vl[1], tA + 1);
        __syncthreads();
    }

    float linv[4];
    #pragma unroll
    for (int r = 0; r < 4; r++) {
        float s2 = lpart[r];
        s2 += __shfl_xor(s2, 1);
        s2 += __shfl_xor(s2, 2);
        s2 += __shfl_xor(s2, 4);
        s2 += __shfl_xor(s2, 8);
        linv[r] = 1.f / s2;
    }
    #pragma unroll
    for (int dt = 0; dt < 4; dt++)
        #pragma unroll
        for (int r = 0; r < 4; r++) {
            float o = oacc[dt][r] * linv[r];
            int sq = qw + 4 * g + r;
            ybuf[((size_t)b_ * NSEQ + sq) * CDIM + h_ * HDIM + 16 * dt + li] = f2bf(o);
        }
#undef STAGE_KV
#undef COMPUTE_TILE
}

// ---------------------------------------------------------------------------
// Proj GEMM: r19 body + XCD-chunked flat grid (384 = 8 x 48, bijective):
// n = s%6, m = s/6 -> pwt (1.2MB) L2-resident per XCD.
// ---------------------------------------------------------------------------
__global__ __launch_bounds__(256) void proj_gemm(
    const unsigned short* __restrict__ yb,   // [4096][768]
    const unsigned short* __restrict__ pwt,  // [768][768] (n,k)
    const float* __restrict__ bias, float* __restrict__ out)
{
    __shared__ unsigned short A0[64 * 32], A1[64 * 32];
    __shared__ unsigned short B0[128 * 32], B1[128 * 32];
    const int tid  = threadIdx.x;
    const int lane = tid & 63;
    const int wid  = tid >> 6;
    const int wr = (wid >> 1) * 32, wc = (wid & 1) * 64;
    const int g = lane >> 4, li = lane & 15;

    const int lin = blockIdx.x;
    const int sdec = (lin & 7) * 48 + (lin >> 3);
    const int n0 = (sdec % 6) * 128;
    const int m0 = (sdec / 6) * 64;

    const int srow = lane >> 2;
    const int scol = ((lane & 3) ^ ((lane >> 3) & 3)) * 8;
    const int rsl  = (g ^ ((li >> 1) & 3)) * 8;

#define PSTAGE(K0, AD, BD)                                                     \
    {                                                                          \
        GLOAD_LDS16(&yb[(size_t)(m0 + wid * 16 + srow) * CDIM + (K0) + scol],  \
                    (AD) + wid * 16 * 32);                                     \
        _Pragma("unroll") for (int c = 0; c < 2; c++)                          \
            GLOAD_LDS16(&pwt[(size_t)(n0 + wid * 32 + c * 16 + srow) * CDIM + (K0) + scol], \
                        (BD) + (wid * 32 + c * 16) * 32);                      \
    }

#define PCOMPUTE(AS, BS)                                                       \
    {                                                                          \
        bf16x8 a[2], b[4];                                                     \
        _Pragma("unroll") for (int mt = 0; mt < 2; mt++)                       \
            a[mt] = *reinterpret_cast<const bf16x8*>(                          \
                (AS) + (wr + 16 * mt + li) * 32 + rsl);                        \
        _Pragma("unroll") for (int nt = 0; nt < 4; nt++)                       \
            b[nt] = *reinterpret_cast<const bf16x8*>(                          \
                (BS) + (wc + 16 * nt + li) * 32 + rsl);                        \
        _Pragma("unroll") for (int mt = 0; mt < 2; mt++)                       \
            _Pragma("unroll") for (int nt = 0; nt < 4; nt++)                   \
                acc[mt][nt] = __builtin_amdgcn_mfma_f32_16x16x32_bf16(         \
                    a[mt], b[nt], acc[mt][nt], 0, 0, 0);                       \
    }

    f32x4 acc[2][4];
    #pragma unroll
    for (int i = 0; i < 2; i++)
        #pragma unroll
        for (int j = 0; j < 4; j++) acc[i][j] = f32x4{0.f, 0.f, 0.f, 0.f};

    PSTAGE(0, A0, B0);
    __syncthreads();

    for (int j = 0; j < 12; ++j) {
        const int k0 = j * 64;
        PSTAGE(k0 + 32, A1, B1);
        PCOMPUTE(A0, B0);
        __syncthreads();
        if (j < 11) PSTAGE(k0 + 64, A0, B0);
        PCOMPUTE(A1, B1);
        __syncthreads();
    }

    #pragma unroll
    for (int mt = 0; mt < 2; mt++)
        #pragma unroll
        for (int nt = 0; nt < 4; nt++) {
            int col = n0 + wc + 16 * nt + li;
            float bv = bias[col];
            #pragma unroll
            for (int r = 0; r < 4; r++) {
                int m = m0 + wr + 16 * mt + 4 * g + r;
                out[(size_t)m * CDIM + col] = acc[mt][nt][r] + bv;
            }
        }
#undef PSTAGE
#undef PCOMPUTE
}

extern "C" void kernel_launch(void* const* d_in, const int* in_sizes, int n_in,
                              void* d_out, int out_size, void* d_ws, size_t ws_size,
                              hipStream_t stream) {
    const float* x         = (const float*)d_in[0];
    const float* attn_bias = (const float*)d_in[1];
    const float* qkv_w     = (const float*)d_in[2];
    const float* qkv_b     = (const float*)d_in[3];
    const float* proj_w    = (const float*)d_in[4];
    const float* proj_b    = (const float*)d_in[5];
    float* out = (float*)d_out;

    const size_t per = (size_t)BATCH * NHEAD * NSEQ * HDIM;  // 3,145,728
    unsigned short* qbuf  = (unsigned short*)d_ws;
    unsigned short* kbuf  = qbuf + per;
    unsigned short* vtbuf = kbuf + per;
    unsigned short* xb    = vtbuf + per;
    unsigned short* qwt   = xb + per;                    // [2304][768]
    unsigned short* pwt   = qwt + (size_t)QKVN * CDIM;   // [768][768]
    unsigned short* ybuf  = xb;  // x dead after qkv_gemm

    prep_kernel<<<NB_X + NB_QW + NB_PW, 256, 0, stream>>>(
        x, xb, qkv_w, qwt, proj_w, pwt);

    qkv_gemm<<<1152, 256, 0, stream>>>(
        xb, qwt, qkv_b, qbuf, kbuf, vtbuf);
    attn_kernel<<<768, 256, 0, stream>>>(
        qbuf, kbuf, vtbuf, attn_bias, ybuf);
    proj_gemm<<<384, 256, 0, stream>>>(
        ybuf, pwt, proj_b, out);
}

// Round 23
// 93.039 us; speedup vs baseline: 1.1494x; 1.0123x over previous
//
#include <hip/hip_runtime.h>
#include <hip/hip_bf16.h>

// Problem constants
constexpr int BATCH = 4;
constexpr int NSEQ  = 1024;
constexpr int CDIM  = 768;
constexpr int NHEAD = 12;
constexpr int HDIM  = 64;
constexpr int MTOT  = BATCH * NSEQ;   // 4096
constexpr int QKVN  = 3 * CDIM;       // 2304

typedef __bf16 bf16x8 __attribute__((ext_vector_type(8)));
typedef float  f32x4  __attribute__((ext_vector_type(4)));

__device__ __forceinline__ unsigned short f2bf(float f) {
    unsigned u = __builtin_bit_cast(unsigned, f);
    unsigned r = u + 0x7FFFu + ((u >> 16) & 1u);   // RNE
    return (unsigned short)(r >> 16);
}

#define GLOAD_LDS16(gp, lp)                                                    \
    __builtin_amdgcn_global_load_lds(                                          \
        (const __attribute__((address_space(1))) void*)(gp),                   \
        (__attribute__((address_space(3))) void*)(lp), 16, 0, 0)

// ---------------------------------------------------------------------------
// Fused prologue: ONE kernel does all three conversions (r18 win).
// ---------------------------------------------------------------------------
constexpr int NB_X  = MTOT * CDIM / 4 / 256;       // 3072
constexpr int NB_QW = (QKVN / 32) * (CDIM / 32);   // 1728
constexpr int NB_PW = (CDIM / 32) * (CDIM / 32);   // 576

__device__ __forceinline__ void tcvt_tile(
    const float* __restrict__ in, unsigned short* __restrict__ out,
    int R, int C, int c0, int r0, int tid)
{
    __shared__ unsigned short t[32][33];
    const int tc = tid & 31, tr = tid >> 5;  // tr 0..7
    #pragma unroll
    for (int i = 0; i < 4; i++)
        t[tc][tr + 8 * i] = f2bf(in[(size_t)(r0 + tr + 8 * i) * C + c0 + tc]);
    __syncthreads();
    #pragma unroll
    for (int i = 0; i < 4; i++)
        out[(size_t)(c0 + tr + 8 * i) * R + r0 + tc] = t[tr + 8 * i][tc];
}

__global__ __launch_bounds__(256) void prep_kernel(
    const float* __restrict__ x,      unsigned short* __restrict__ xb,
    const float* __restrict__ qkv_w,  unsigned short* __restrict__ qwt,
    const float* __restrict__ proj_w, unsigned short* __restrict__ pwt)
{
    const int bid = blockIdx.x;
    const int tid = threadIdx.x;
    if (bid < NB_X) {
        int i = bid * 256 + tid;
        float4 a = reinterpret_cast<const float4*>(x)[i];
        ushort4 h;
        h.x = f2bf(a.x); h.y = f2bf(a.y); h.z = f2bf(a.z); h.w = f2bf(a.w);
        reinterpret_cast<ushort4*>(xb)[i] = h;
    } else if (bid < NB_X + NB_QW) {
        int t = bid - NB_X;
        tcvt_tile(qkv_w, qwt, CDIM, QKVN, (t % (QKVN / 32)) * 32,
                  (t / (QKVN / 32)) * 32, tid);
    } else {
        int t = bid - NB_X - NB_QW;
        tcvt_tile(proj_w, pwt, CDIM, CDIM, (t % (CDIM / 32)) * 32,
                  (t / (CDIM / 32)) * 32, tid);
    }
}

// ---------------------------------------------------------------------------
// QKV GEMM: r22 version (64x128, BK=32, swizzled LDS, 3-deep counted-vmcnt
// pipeline, XCD-chunked flat grid 1152 = 8 x 144).
// ---------------------------------------------------------------------------
__global__ __launch_bounds__(256) void qkv_gemm(
    const unsigned short* __restrict__ xb,   // [4096][768]
    const unsigned short* __restrict__ wt,   // [2304][768]
    const float* __restrict__ bias,
    unsigned short* __restrict__ qbuf, unsigned short* __restrict__ kbuf,
    unsigned short* __restrict__ vtbuf)
{
    __shared__ unsigned short A0[64 * 32], A1[64 * 32], A2[64 * 32];
    __shared__ unsigned short B0[128 * 32], B1[128 * 32], B2[128 * 32];
    const int tid  = threadIdx.x;
    const int lane = tid & 63;
    const int wid  = tid >> 6;
    const int wr = (wid >> 1) * 32, wc = (wid & 1) * 64;
    const int g = lane >> 4, li = lane & 15;

    const int lin = blockIdx.x;
    const int sdec = (lin & 7) * 144 + (lin >> 3);
    const int n0 = (sdec % 18) * 128;
    const int m0 = (sdec / 18) * 64;

    const int srow = lane >> 2;                               // 0..15
    const int scol = ((lane & 3) ^ ((lane >> 3) & 3)) * 8;    // swizzled src col
    const int rsl  = (g ^ ((li >> 1) & 3)) * 8;               // swizzled read col

#define QSTAGE(K0, AD, BD)                                                     \
    {                                                                          \
        GLOAD_LDS16(&xb[(size_t)(m0 + wid * 16 + srow) * CDIM + (K0) + scol],  \
                    (AD) + wid * 16 * 32);                                     \
        _Pragma("unroll") for (int c = 0; c < 2; c++)                          \
            GLOAD_LDS16(&wt[(size_t)(n0 + wid * 32 + c * 16 + srow) * CDIM + (K0) + scol], \
                        (BD) + (wid * 32 + c * 16) * 32);                      \
    }

#define QCOMPUTE(AS, BS)                                                       \
    {                                                                          \
        bf16x8 a[2], b[4];                                                     \
        _Pragma("unroll") for (int mt = 0; mt < 2; mt++)                       \
            a[mt] = *reinterpret_cast<const bf16x8*>(                          \
                (AS) + (wr + 16 * mt + li) * 32 + rsl);                        \
        _Pragma("unroll") for (int nt = 0; nt < 4; nt++)                       \
            b[nt] = *reinterpret_cast<const bf16x8*>(                          \
                (BS) + (wc + 16 * nt + li) * 32 + rsl);                        \
        _Pragma("unroll") for (int mt = 0; mt < 2; mt++)                       \
            _Pragma("unroll") for (int nt = 0; nt < 4; nt++)                   \
                acc[mt][nt] = __builtin_amdgcn_mfma_f32_16x16x32_bf16(         \
                    a[mt], b[nt], acc[mt][nt], 0, 0, 0);                       \
    }

#define WAITBAR3()                                                             \
    {                                                                          \
        asm volatile("s_waitcnt vmcnt(3)" ::: "memory");                       \
        __builtin_amdgcn_sched_barrier(0);                                     \
        __builtin_amdgcn_s_barrier();                                          \
        __builtin_amdgcn_sched_barrier(0);                                     \
    }
#define WAITBAR0()                                                             \
    {                                                                          \
        asm volatile("s_waitcnt vmcnt(0)" ::: "memory");                       \
        __builtin_amdgcn_sched_barrier(0);                                     \
        __builtin_amdgcn_s_barrier();                                          \
        __builtin_amdgcn_sched_barrier(0);                                     \
    }

    f32x4 acc[2][4];
    #pragma unroll
    for (int i = 0; i < 2; i++)
        #pragma unroll
        for (int j = 0; j < 4; j++) acc[i][j] = f32x4{0.f, 0.f, 0.f, 0.f};

    QSTAGE(0, A0, B0);
    QSTAGE(32, A1, B1);
    WAITBAR3();

    for (int j = 0; j < 8; ++j) {
        const int k0 = j * 96;
        QSTAGE(k0 + 64, A2, B2);
        QCOMPUTE(A0, B0);
        WAITBAR3();
        if (j < 7) {
            QSTAGE(k0 + 96, A0, B0);
            QCOMPUTE(A1, B1);
            WAITBAR3();
            QSTAGE(k0 + 128, A1, B1);
            QCOMPUTE(A2, B2);
            WAITBAR3();
        } else {
            QCOMPUTE(A1, B1);
            WAITBAR0();
            QCOMPUTE(A2, B2);
        }
    }

    #pragma unroll
    for (int mt = 0; mt < 2; mt++) {
        #pragma unroll
        for (int nt = 0; nt < 4; nt++) {
            int col  = n0 + wc + 16 * nt + li;
            int tsel = col / CDIM;
            int rem  = col - tsel * CDIM;
            int h_ = rem >> 6, d = rem & 63;
            float bv = bias[col];
            float sc = (tsel == 0) ? 0.125f : 1.0f;
            #pragma unroll
            for (int r = 0; r < 4; r++) {
                int m  = m0 + wr + 16 * mt + 4 * g + r;
                int b_ = m >> 10, s = m & 1023;
                unsigned short hv = f2bf((acc[mt][nt][r] + bv) * sc);
                if (tsel == 0)
                    qbuf[(((size_t)b_ * NHEAD + h_) * NSEQ + s) * HDIM + d] = hv;
                else if (tsel == 1)
                    kbuf[(((size_t)b_ * NHEAD + h_) * NSEQ + s) * HDIM + d] = hv;
                else
                    vtbuf[(((size_t)b_ * NHEAD + h_) * HDIM + d) * NSEQ + s] = hv;
            }
        }
    }
#undef QSTAGE
#undef QCOMPUTE
#undef WAITBAR3
#undef WAITBAR0
}

// ---------------------------------------------------------------------------
// Flash-style attention — r21/r22 version + T5 s_setprio around the MFMA
// clusters (attn only: resident blocks run at independent phases, so the CU
// scheduler can favor MFMA-entering waves; m191 measured +4-7% on attn,
// m190 showed null on lockstep GEMM -> not applied to qkv/proj).
// ---------------------------------------------------------------------------
__global__ __launch_bounds__(256, 3) void attn_kernel(
    const unsigned short* __restrict__ qbuf,
    const unsigned short* __restrict__ kbuf,
    const unsigned short* __restrict__ vtbuf,
    const float* __restrict__ bias,     // [H,N,N]
    unsigned short* __restrict__ ybuf)  // [B,N,C] bf16
{
    __shared__ unsigned short Kl[2][64 * 64];  // [k][d] linear, source-swizzled
    __shared__ unsigned short Vl[2][64 * 64];  // V^T [d][k] linear, swizzled
    __shared__ unsigned short Ps[4][16][72];   // per-wave P: [q][k]

    const int tid  = threadIdx.x;
    const int lane = tid & 63;
    const int wid  = tid >> 6;
    const int g = lane >> 4, li = lane & 15;
    const int srow8 = lane >> 3;               // 0..7
    const int scs   = (lane & 7) ^ srow8;      // swizzled source slot (16B units)

    // XCD-chunked decode: s = b + 4*(qtile+16*h), bijective (768 = 8 x 96)
    const int lin = blockIdx.x;
    const int s   = (lin & 7) * 96 + (lin >> 3);
    const int b_    = s & 3;
    const int qtile = (s >> 2) & 15;
    const int h_    = s >> 6;                  // 0..11
    const int bh    = b_ * NHEAD + h_;
    const int qw = qtile * 64 + wid * 16;

    const unsigned short* qb = qbuf + (size_t)bh * NSEQ * HDIM;
    const unsigned short* kb = kbuf + (size_t)bh * NSEQ * HDIM;
    const unsigned short* vb = vtbuf + (size_t)bh * HDIM * NSEQ;
    const float* bb = bias + (size_t)h_ * NSEQ * NSEQ;

#define STAGE_KV(T, KL, VL)                                                    \
    {                                                                          \
        _Pragma("unroll") for (int i = 0; i < 2; i++) {                        \
            GLOAD_LDS16(kb + (size_t)((T) * 64 + wid * 16 + i * 8 + srow8) * HDIM + scs * 8, \
                        (KL) + (wid * 16 + i * 8) * 64);                       \
            GLOAD_LDS16(vb + (size_t)(wid * 16 + i * 8 + srow8) * NSEQ + (T) * 64 + scs * 8, \
                        (VL) + (wid * 16 + i * 8) * 64);                       \
        }                                                                      \
    }

#define COMPUTE_TILE(KS, VS, T)                                                \
    {                                                                          \
        float bv[4][4];                                                        \
        _Pragma("unroll") for (int kt = 0; kt < 4; kt++)                       \
            _Pragma("unroll") for (int r = 0; r < 4; r++)                      \
                bv[kt][r] = bb[(size_t)(qw + 4 * g + r) * NSEQ + (T) * 64 + 16 * kt + li]; \
        f32x4 sacc[4];                                                         \
        _Pragma("unroll") for (int kt = 0; kt < 4; kt++)                       \
            sacc[kt] = f32x4{0.f, 0.f, 0.f, 0.f};                              \
        __builtin_amdgcn_s_setprio(1);                                         \
        _Pragma("unroll") for (int kt = 0; kt < 4; kt++)                       \
            _Pragma("unroll") for (int dd = 0; dd < 2; dd++) {                 \
                bf16x8 kf = *reinterpret_cast<const bf16x8*>(                  \
                    (KS) + (16 * kt + li) * 64 + (((4 * dd + g) ^ (li & 7)) * 8)); \
                sacc[kt] = __builtin_amdgcn_mfma_f32_16x16x32_bf16(qf[dd], kf, sacc[kt], 0, 0, 0); \
            }                                                                  \
        __builtin_amdgcn_s_setprio(0);                                         \
        _Pragma("unroll") for (int kt = 0; kt < 4; kt++)                       \
            _Pragma("unroll") for (int r = 0; r < 4; r++) {                    \
                float pv = __expf(sacc[kt][r] + bv[kt][r]);                    \
                lpart[r] += pv;                                                \
                Ps[wid][4 * g + r][16 * kt + li] = f2bf(pv);                   \
            }                                                                  \
        __builtin_amdgcn_s_setprio(1);                                         \
        _Pragma("unroll") for (int kk = 0; kk < 2; kk++) {                     \
            bf16x8 pf = *reinterpret_cast<const bf16x8*>(&Ps[wid][li][32 * kk + 8 * g]); \
            _Pragma("unroll") for (int dt = 0; dt < 4; dt++) {                 \
                bf16x8 vf = *reinterpret_cast<const bf16x8*>(                  \
                    (VS) + (16 * dt + li) * 64 + (((4 * kk + g) ^ (li & 7)) * 8)); \
                oacc[dt] = __builtin_amdgcn_mfma_f32_16x16x32_bf16(pf, vf, oacc[dt], 0, 0, 0); \
            }                                                                  \
        }                                                                      \
        __builtin_amdgcn_s_setprio(0);                                         \
    }

    bf16x8 qf[2];
    #pragma unroll
    for (int dd = 0; dd < 2; dd++)
        qf[dd] = *reinterpret_cast<const bf16x8*>(&qb[(size_t)(qw + li) * HDIM + 32 * dd + 8 * g]);

    f32x4 oacc[4];
    #pragma unroll
    for (int dt = 0; dt < 4; dt++) oacc[dt] = f32x4{0.f, 0.f, 0.f, 0.f};
    float lpart[4] = {0.f, 0.f, 0.f, 0.f};

    STAGE_KV(0, Kl[0], Vl[0]);
    __syncthreads();

    for (int j = 0; j < 8; ++j) {
        const int tA = 2 * j;
        STAGE_KV(tA + 1, Kl[1], Vl[1]);
        COMPUTE_TILE(Kl[0], Vl[0], tA);
        __syncthreads();

        if (j < 7) STAGE_KV(tA + 2, Kl[0], Vl[0]);
        COMPUTE_TILE(Kl[1], Vl[1], tA + 1);
        __syncthreads();
    }

    float linv[4];
    #pragma unroll
    for (int r = 0; r < 4; r++) {
        float s2 = lpart[r];
        s2 += __shfl_xor(s2, 1);
        s2 += __shfl_xor(s2, 2);
        s2 += __shfl_xor(s2, 4);
        s2 += __shfl_xor(s2, 8);
        linv[r] = 1.f / s2;
    }
    #pragma unroll
    for (int dt = 0; dt < 4; dt++)
        #pragma unroll
        for (int r = 0; r < 4; r++) {
            float o = oacc[dt][r] * linv[r];
            int sq = qw + 4 * g + r;
            ybuf[((size_t)b_ * NSEQ + sq) * CDIM + h_ * HDIM + 16 * dt + li] = f2bf(o);
        }
#undef STAGE_KV
#undef COMPUTE_TILE
}

// ---------------------------------------------------------------------------
// Proj GEMM: r22 version (64x128 tile, BK=32, async dbuf, 2-way swizzle,
// XCD-chunked flat grid 384 = 8 x 48).
// ---------------------------------------------------------------------------
__global__ __launch_bounds__(256) void proj_gemm(
    const unsigned short* __restrict__ yb,   // [4096][768]
    const unsigned short* __restrict__ pwt,  // [768][768] (n,k)
    const float* __restrict__ bias, float* __restrict__ out)
{
    __shared__ unsigned short A0[64 * 32], A1[64 * 32];
    __shared__ unsigned short B0[128 * 32], B1[128 * 32];
    const int tid  = threadIdx.x;
    const int lane = tid & 63;
    const int wid  = tid >> 6;
    const int wr = (wid >> 1) * 32, wc = (wid & 1) * 64;
    const int g = lane >> 4, li = lane & 15;

    const int lin = blockIdx.x;
    const int sdec = (lin & 7) * 48 + (lin >> 3);
    const int n0 = (sdec % 6) * 128;
    const int m0 = (sdec / 6) * 64;

    const int srow = lane >> 2;
    const int scol = ((lane & 3) ^ ((lane >> 3) & 3)) * 8;
    const int rsl  = (g ^ ((li >> 1) & 3)) * 8;

#define PSTAGE(K0, AD, BD)                                                     \
    {                                                                          \
        GLOAD_LDS16(&yb[(size_t)(m0 + wid * 16 + srow) * CDIM + (K0) + scol],  \
                    (AD) + wid * 16 * 32);                                     \
        _Pragma("unroll") for (int c = 0; c < 2; c++)                          \
            GLOAD_LDS16(&pwt[(size_t)(n0 + wid * 32 + c * 16 + srow) * CDIM + (K0) + scol], \
                        (BD) + (wid * 32 + c * 16) * 32);                      \
    }

#define PCOMPUTE(AS, BS)                                                       \
    {                                                                          \
        bf16x8 a[2], b[4];                                                     \
        _Pragma("unroll") for (int mt = 0; mt < 2; mt++)                       \
            a[mt] = *reinterpret_cast<const bf16x8*>(                          \
                (AS) + (wr + 16 * mt + li) * 32 + rsl);                        \
        _Pragma("unroll") for (int nt = 0; nt < 4; nt++)                       \
            b[nt] = *reinterpret_cast<const bf16x8*>(                          \
                (BS) + (wc + 16 * nt + li) * 32 + rsl);                        \
        _Pragma("unroll") for (int mt = 0; mt < 2; mt++)                       \
            _Pragma("unroll") for (int nt = 0; nt < 4; nt++)                   \
                acc[mt][nt] = __builtin_amdgcn_mfma_f32_16x16x32_bf16(         \
                    a[mt], b[nt], acc[mt][nt], 0, 0, 0);                       \
    }

    f32x4 acc[2][4];
    #pragma unroll
    for (int i = 0; i < 2; i++)
        #pragma unroll
        for (int j = 0; j < 4; j++) acc[i][j] = f32x4{0.f, 0.f, 0.f, 0.f};

    PSTAGE(0, A0, B0);
    __syncthreads();

    for (int j = 0; j < 12; ++j) {
        const int k0 = j * 64;
        PSTAGE(k0 + 32, A1, B1);
        PCOMPUTE(A0, B0);
        __syncthreads();
        if (j < 11) PSTAGE(k0 + 64, A0, B0);
        PCOMPUTE(A1, B1);
        __syncthreads();
    }

    #pragma unroll
    for (int mt = 0; mt < 2; mt++)
        #pragma unroll
        for (int nt = 0; nt < 4; nt++) {
            int col = n0 + wc + 16 * nt + li;
            float bv = bias[col];
            #pragma unroll
            for (int r = 0; r < 4; r++) {
                int m = m0 + wr + 16 * mt + 4 * g + r;
                out[(size_t)m * CDIM + col] = acc[mt][nt][r] + bv;
            }
        }
#undef PSTAGE
#undef PCOMPUTE
}

extern "C" void kernel_launch(void* const* d_in, const int* in_sizes, int n_in,
                              void* d_out, int out_size, void* d_ws, size_t ws_size,
                              hipStream_t stream) {
    const float* x         = (const float*)d_in[0];
    const float* attn_bias = (const float*)d_in[1];
    const float* qkv_w     = (const float*)d_in[2];
    const float* qkv_b     = (const float*)d_in[3];
    const float* proj_w    = (const float*)d_in[4];
    const float* proj_b    = (const float*)d_in[5];
    float* out = (float*)d_out;

    const size_t per = (size_t)BATCH * NHEAD * NSEQ * HDIM;  // 3,145,728
    unsigned short* qbuf  = (unsigned short*)d_ws;
    unsigned short* kbuf  = qbuf + per;
    unsigned short* vtbuf = kbuf + per;
    unsigned short* xb    = vtbuf + per;
    unsigned short* qwt   = xb + per;                    // [2304][768]
    unsigned short* pwt   = qwt + (size_t)QKVN * CDIM;   // [768][768]
    unsigned short* ybuf  = xb;  // x dead after qkv_gemm

    prep_kernel<<<NB_X + NB_QW + NB_PW, 256, 0, stream>>>(
        x, xb, qkv_w, qwt, proj_w, pwt);

    qkv_gemm<<<1152, 256, 0, stream>>>(
        xb, qwt, qkv_b, qbuf, kbuf, vtbuf);
    attn_kernel<<<768, 256, 0, stream>>>(
        qbuf, kbuf, vtbuf, attn_bias, ybuf);
    proj_gemm<<<384, 256, 0, stream>>>(
        ybuf, pwt, proj_b, out);
}